// Round 7
// baseline (1166.580 us; speedup 1.0000x reference)
//
#include <hip/hip_runtime.h>
#include <stdint.h>

// GraphConv x5 on MI355X — round 7.
// vs round 6: k_pre2 (wave-per-node, readlane broadcasts; compiler refused to
// keep weights in VGPRs -> VGPR=36, reloads, 67us) replaced by k_pre3:
// lane = NODE, channel loop. W[c][k] is wave-uniform -> SGPRs via s_load
// (scalar pipe), v_fmac takes the weight as SGPR operand: exactly 1 VALU op
// per FMA, no readlane. h-row in 64 VGPRs per lane, H read ONCE for both
// G (bf16) and R (fp32). Outputs transposed through 8.3KB padded LDS
// (stride 65 -> conflict-free) for full-line coalesced stores.

#define NN 100000
#define NE 1600000
#define HID 64
#define NBKT 391            // ceil(NN/256), bucket = dst >> 8
#define TILE 4096
#define EPT 16              // TILE / 256
#define NTILE ((NE + TILE - 1) / TILE)   // 391
#define NPRE ((NN + 63) / 64)            // 1563 pre-transform tiles

// ---------------- CSR build ----------------

__global__ __launch_bounds__(256) void k_bhist(const int* __restrict__ dst,
                                               int* __restrict__ bcnt) {
    __shared__ int h[NBKT];
    for (int t = threadIdx.x; t < NBKT; t += 256) h[t] = 0;
    __syncthreads();
    int stride = gridDim.x * blockDim.x;
    for (int e = blockIdx.x * blockDim.x + threadIdx.x; e < NE; e += stride)
        atomicAdd(&h[dst[e] >> 8], 1);
    __syncthreads();
    for (int t = threadIdx.x; t < NBKT; t += 256)
        if (h[t]) atomicAdd(&bcnt[t], h[t]);
}

__global__ void k_bscan(const int* __restrict__ bcnt, int* __restrict__ bbase,
                        int* __restrict__ bcur, int* __restrict__ offs) {
    __shared__ int tmp[512];
    int t = threadIdx.x;
    int v = (t < NBKT) ? bcnt[t] : 0;
    int acc = v;
    tmp[t] = v;
    __syncthreads();
    for (int off = 1; off < 512; off <<= 1) {
        int u = (t >= off) ? tmp[t - off] : 0;
        __syncthreads();
        acc += u;
        tmp[t] = acc;
        __syncthreads();
    }
    if (t < NBKT) {
        bbase[t] = acc - v;
        bcur[t]  = acc - v;
    }
    if (t == 0) { bbase[NBKT] = NE; offs[NN] = NE; }
}

// tile-local partition: one block per 4096-edge tile
__global__ __launch_bounds__(256) void k_bpart(const int* __restrict__ src,
                                               const int* __restrict__ dst,
                                               const float* __restrict__ w,
                                               int* __restrict__ bcur,
                                               int2* __restrict__ bpairs) {
    __shared__ int hcnt[NBKT];
    __shared__ int hbase[NBKT];
    int tile0 = blockIdx.x * TILE;
    for (int t = threadIdx.x; t < NBKT; t += 256) hcnt[t] = 0;
    __syncthreads();

    int   pk[EPT];
    int   bk[EPT];
    float wv[EPT];
    #pragma unroll
    for (int k = 0; k < EPT; k++) {
        int e = tile0 + threadIdx.x + k * 256;
        if (e < NE) {
            int d = dst[e];
            int b = d >> 8;
            pk[k] = (src[e] << 8) | (d & 255);
            wv[k] = w[e];
            bk[k] = b;
            atomicAdd(&hcnt[b], 1);
        } else {
            bk[k] = -1;
        }
    }
    __syncthreads();
    for (int t = threadIdx.x; t < NBKT; t += 256) {
        int c = hcnt[t];
        hbase[t] = c ? atomicAdd(&bcur[t], c) : 0;
        hcnt[t] = 0;
    }
    __syncthreads();
    #pragma unroll
    for (int k = 0; k < EPT; k++) {
        if (bk[k] >= 0) {
            int pos = hbase[bk[k]] + atomicAdd(&hcnt[bk[k]], 1);
            bpairs[pos] = make_int2(pk[k], __float_as_int(wv[k]));
        }
    }
}

// one block per bucket: LDS counting sort over 256 local dst
__global__ __launch_bounds__(256) void k_bcsr(const int* __restrict__ bbase,
                                              const int2* __restrict__ bpairs,
                                              int* __restrict__ offs,
                                              int2* __restrict__ pairs) {
    __shared__ int cnt[256];
    __shared__ int scn[256];
    __shared__ int cur[256];
    int k = blockIdx.x, t = threadIdx.x;
    int b = bbase[k], e = bbase[k + 1];
    cnt[t] = 0;
    __syncthreads();
    for (int j = b + t; j < e; j += 256)
        atomicAdd(&cnt[bpairs[j].x & 255], 1);
    __syncthreads();
    int v = cnt[t], acc = v;
    scn[t] = v;
    __syncthreads();
    for (int off = 1; off < 256; off <<= 1) {
        int u = (t >= off) ? scn[t - off] : 0;
        __syncthreads();
        acc += u;
        scn[t] = acc;
        __syncthreads();
    }
    int excl = acc - v;
    cur[t] = excl;
    int d = (k << 8) + t;
    if (d < NN) offs[d] = b + excl;
    __syncthreads();
    for (int j = b + t; j < e; j += 256) {
        int2 q = bpairs[j];
        int pos = b + atomicAdd(&cur[q.x & 255], 1);
        pairs[pos] = make_int2(q.x >> 8, q.y);
    }
}

// ---------------- layers ----------------

__global__ void k_agg_scalar(const int* __restrict__ offs, const int2* __restrict__ pairs,
                             const float* __restrict__ val, float* __restrict__ out) {
    int i = blockIdx.x * blockDim.x + threadIdx.x;
    if (i >= NN) return;
    float a0 = 0.f, a1 = 0.f;
    int b = offs[i], e = offs[i + 1];
    int j = b;
    for (; j + 2 <= e; j += 2) {
        int2 p0 = pairs[j], p1 = pairs[j + 1];
        a0 += __int_as_float(p0.y) * val[p0.x];
        a1 += __int_as_float(p1.y) * val[p1.x];
    }
    for (; j < e; j++) {
        int2 p = pairs[j];
        a0 += __int_as_float(p.y) * val[p.x];
    }
    out[i] = a0 + a1;
}

__global__ void k_layer0(const float* __restrict__ agg0, const float* __restrict__ x,
                         const float* __restrict__ Wrel0, const float* __restrict__ brel0,
                         const float* __restrict__ Wroot0, float* __restrict__ h) {
    int idx = blockIdx.x * blockDim.x + threadIdx.x;  // NN*64 exact
    int i = idx >> 6, c = idx & 63;
    float v = agg0[i] * Wrel0[c] + brel0[c] + x[i] * Wroot0[c];
    h[idx] = v > 0.f ? v : 0.f;
}

// Pre-transform, transposed: one wave per 64-node tile, lane = node.
// h-row (64 fp32) in VGPRs; weights stream through SGPRs (wave-uniform
// s_load), 1 v_fmac per MAC. G packed bf16 pairs, R fp32; both transposed
// through padded LDS (stride 65) for coalesced full-line global stores.
__global__ __launch_bounds__(64, 4) void k_pre3(
        const float* __restrict__ hin, const float* __restrict__ Wrel,
        const float* __restrict__ Wroot, const float* __restrict__ brel,
        uint32_t* __restrict__ Gb32, float* __restrict__ R) {
    __shared__ uint32_t sst[32 * 65];   // 8320 B
    const int i = threadIdx.x;          // lane = local node
    const int tile0 = blockIdx.x * 64;
    const int node = tile0 + i;
    const bool valid = node < NN;

    float h[64];
    if (valid) {
        #pragma unroll
        for (int k4 = 0; k4 < 16; k4++) {
            float4 v = *(const float4*)&hin[node * 64 + k4 * 4];
            h[k4 * 4 + 0] = v.x; h[k4 * 4 + 1] = v.y;
            h[k4 * 4 + 2] = v.z; h[k4 * 4 + 3] = v.w;
        }
    } else {
        #pragma unroll
        for (int k = 0; k < 64; k++) h[k] = 0.f;
    }

    // ---- role G: Gb[node][c] = bf16(sum_k Wrel[c][k] * h[k]) ----
    for (int half = 0; half < 2; half++) {
        #pragma unroll 1
        for (int cp = 0; cp < 16; cp++) {
            int c = half * 32 + cp * 2;
            float a0 = 0.f, a1 = 0.f, b0 = 0.f, b1 = 0.f;
            #pragma unroll
            for (int k4 = 0; k4 < 16; k4++) {
                float4 wa = *(const float4*)&Wrel[c * 64 + k4 * 4];
                float4 wb = *(const float4*)&Wrel[(c + 1) * 64 + k4 * 4];
                a0 += h[k4 * 4 + 0] * wa.x; a1 += h[k4 * 4 + 1] * wa.y;
                a0 += h[k4 * 4 + 2] * wa.z; a1 += h[k4 * 4 + 3] * wa.w;
                b0 += h[k4 * 4 + 0] * wb.x; b1 += h[k4 * 4 + 1] * wb.y;
                b0 += h[k4 * 4 + 2] * wb.z; b1 += h[k4 * 4 + 3] * wb.w;
            }
            uint32_t ua = __float_as_uint(a0 + a1);
            uint32_t ub = __float_as_uint(b0 + b1);
            ua = (ua + 0x7fffu + ((ua >> 16) & 1u)) >> 16;   // RNE to bf16
            ub = (ub + 0x7fffu + ((ub >> 16) & 1u)) >> 16;
            sst[cp * 65 + i] = (ub << 16) | ua;              // (i+cp)%32: free
        }
        #pragma unroll 1
        for (int j = 0; j < 16; j++) {
            int pwl = i & 15, nl = 4 * j + (i >> 4);
            uint32_t v = sst[pwl * 65 + nl];
            int nd = tile0 + nl;
            if (nd < NN) Gb32[nd * 32 + half * 16 + pwl] = v;  // 4 full lines
        }
    }

    // ---- role R: R[node][c] = sum_k Wroot[c][k]*h[k] + brel[c] ----
    for (int half = 0; half < 2; half++) {
        #pragma unroll 1
        for (int cp = 0; cp < 16; cp++) {
            int c = half * 32 + cp * 2;
            float a0 = brel[c], a1 = 0.f, b0 = brel[c + 1], b1 = 0.f;
            #pragma unroll
            for (int k4 = 0; k4 < 16; k4++) {
                float4 wa = *(const float4*)&Wroot[c * 64 + k4 * 4];
                float4 wb = *(const float4*)&Wroot[(c + 1) * 64 + k4 * 4];
                a0 += h[k4 * 4 + 0] * wa.x; a1 += h[k4 * 4 + 1] * wa.y;
                a0 += h[k4 * 4 + 2] * wa.z; a1 += h[k4 * 4 + 3] * wa.w;
                b0 += h[k4 * 4 + 0] * wb.x; b1 += h[k4 * 4 + 1] * wb.y;
                b0 += h[k4 * 4 + 2] * wb.z; b1 += h[k4 * 4 + 3] * wb.w;
            }
            int cl = cp * 2;
            sst[cl * 65 + i]       = __float_as_uint(a0 + a1);
            sst[(cl + 1) * 65 + i] = __float_as_uint(b0 + b1);
        }
        #pragma unroll 1
        for (int j = 0; j < 32; j++) {
            int cl = i & 31, nl = 2 * j + (i >> 5);
            uint32_t v = sst[cl * 65 + nl];
            int nd = tile0 + nl;
            if (nd < NN) R[nd * 64 + half * 32 + cl] = __uint_as_float(v);
        }
    }
}

// hout[i][c] = relu( sum_j w_j*G[src_j][c] + R[i][c] ), G bf16 (128B rows).
__global__ __launch_bounds__(256) void k_aggrelu(
        const int* __restrict__ offs, const int2* __restrict__ pairs,
        const uint32_t* __restrict__ Gb, const float* __restrict__ R,
        float* __restrict__ hout) {
    int c = threadIdx.x & 63;
    int half = c >> 1;
    int sh = (c & 1) ? 0 : 16;        // g = as_float((u << sh) & 0xffff0000)
    int wid = (blockIdx.x * blockDim.x + threadIdx.x) >> 6;
    int n0 = wid << 2;                // NN % 4 == 0
    if (n0 >= NN) return;
    int ov = (c < 5) ? offs[n0 + c] : 0;
    int bnd[5];
    bnd[0] = __builtin_amdgcn_readlane(ov, 0);
    bnd[1] = __builtin_amdgcn_readlane(ov, 1);
    bnd[2] = __builtin_amdgcn_readlane(ov, 2);
    bnd[3] = __builtin_amdgcn_readlane(ov, 3);
    bnd[4] = __builtin_amdgcn_readlane(ov, 4);

    float accA[4] = {0.f, 0.f, 0.f, 0.f};
    float accB[4] = {0.f, 0.f, 0.f, 0.f};

    for (int cb = bnd[0]; cb < bnd[4]; cb += 64) {
        int n = bnd[4] - cb; if (n > 64) n = 64;
        int2 p = (c < n) ? pairs[cb + c] : make_int2(0, 0);
        #pragma unroll
        for (int t = 0; t < 4; t++) {
            int lo = bnd[t]     > cb     ? bnd[t]     : cb;
            int hi = bnd[t + 1] < cb + n ? bnd[t + 1] : cb + n;
            int j = lo;
            for (; j + 4 <= hi; j += 4) {
                int jj = j - cb;
                int s0 = __builtin_amdgcn_readlane(p.x, jj + 0);
                int s1 = __builtin_amdgcn_readlane(p.x, jj + 1);
                int s2 = __builtin_amdgcn_readlane(p.x, jj + 2);
                int s3 = __builtin_amdgcn_readlane(p.x, jj + 3);
                float w0 = __uint_as_float(__builtin_amdgcn_readlane(p.y, jj + 0));
                float w1 = __uint_as_float(__builtin_amdgcn_readlane(p.y, jj + 1));
                float w2 = __uint_as_float(__builtin_amdgcn_readlane(p.y, jj + 2));
                float w3 = __uint_as_float(__builtin_amdgcn_readlane(p.y, jj + 3));
                uint32_t u0 = Gb[s0 * 32 + half];
                uint32_t u1 = Gb[s1 * 32 + half];
                uint32_t u2 = Gb[s2 * 32 + half];
                uint32_t u3 = Gb[s3 * 32 + half];
                float g0 = __uint_as_float((u0 << sh) & 0xffff0000u);
                float g1 = __uint_as_float((u1 << sh) & 0xffff0000u);
                float g2 = __uint_as_float((u2 << sh) & 0xffff0000u);
                float g3 = __uint_as_float((u3 << sh) & 0xffff0000u);
                accA[t] += w0 * g0;
                accB[t] += w1 * g1;
                accA[t] += w2 * g2;
                accB[t] += w3 * g3;
            }
            for (; j < hi; j++) {
                int jj = j - cb;
                int s = __builtin_amdgcn_readlane(p.x, jj);
                float wv = __uint_as_float(__builtin_amdgcn_readlane(p.y, jj));
                uint32_t u = Gb[s * 32 + half];
                accA[t] += wv * __uint_as_float((u << sh) & 0xffff0000u);
            }
        }
    }
    #pragma unroll
    for (int t = 0; t < 4; t++) {
        float v = accA[t] + accB[t] + R[(n0 + t) * 64 + c];
        hout[(n0 + t) * 64 + c] = v > 0.f ? v : 0.f;
    }
}

__global__ void k_lastdot(const float* __restrict__ h, const float* __restrict__ WrelL,
                          const float* __restrict__ WrootL, float* __restrict__ sarr,
                          float* __restrict__ rarr) {
    int g = blockIdx.x * blockDim.x + threadIdx.x;
    int node = g >> 6, lane = g & 63;
    if (node >= NN) return;
    float v = h[node * 64 + lane];
    float a = v * WrelL[lane];
    float c = v * WrootL[lane];
    for (int o = 32; o > 0; o >>= 1) {
        a += __shfl_down(a, o, 64);
        c += __shfl_down(c, o, 64);
    }
    if (lane == 0) { sarr[node] = a; rarr[node] = c; }
}

__global__ void k_last(const int* __restrict__ offs, const int2* __restrict__ pairs,
                       const float* __restrict__ sarr, const float* __restrict__ rarr,
                       const float* __restrict__ brelL, float* __restrict__ out) {
    int i = blockIdx.x * blockDim.x + threadIdx.x;
    if (i >= NN) return;
    float a0 = rarr[i] + brelL[0], a1 = 0.f;
    int b = offs[i], e = offs[i + 1];
    int j = b;
    for (; j + 2 <= e; j += 2) {
        int2 p0 = pairs[j], p1 = pairs[j + 1];
        a0 += __int_as_float(p0.y) * sarr[p0.x];
        a1 += __int_as_float(p1.y) * sarr[p1.x];
    }
    for (; j < e; j++) {
        int2 p = pairs[j];
        a0 += __int_as_float(p.y) * sarr[p.x];
    }
    out[i] = a0 + a1;
}

extern "C" void kernel_launch(void* const* d_in, const int* in_sizes, int n_in,
                              void* d_out, int out_size, void* d_ws, size_t ws_size,
                              hipStream_t stream) {
    const float* x        = (const float*)d_in[0];
    const int*   ei       = (const int*)d_in[1];
    const float* ew       = (const float*)d_in[2];
    const float* Wrel0    = (const float*)d_in[3];
    const float* brel0    = (const float*)d_in[4];
    const float* Wroot0   = (const float*)d_in[5];
    const float* Wrel_mid = (const float*)d_in[6];
    const float* brel_mid = (const float*)d_in[7];
    const float* Wroot_mid= (const float*)d_in[8];
    const float* WrelL    = (const float*)d_in[9];
    const float* brelL    = (const float*)d_in[10];
    const float* WrootL   = (const float*)d_in[11];
    float* out = (float*)d_out;

    const int* src  = ei;
    const int* dstp = ei + NE;

    char* w = (char*)d_ws;
    size_t o = 0;
    auto alloc = [&](size_t b) -> void* {
        void* r = (void*)(w + o);
        o += (b + 255) & ~(size_t)255;
        return r;
    };
    int*      offs  = (int*)alloc((size_t)(NN + 1) * 4);
    int*      bcnt  = (int*)alloc((size_t)NBKT * 4);
    int*      bbase = (int*)alloc((size_t)(NBKT + 1) * 4);
    int*      bcur  = (int*)alloc((size_t)NBKT * 4);
    int2*     pairs = (int2*)alloc((size_t)NE * 8);
    float*    H     = (float*)alloc((size_t)NN * HID * 4);   // 25.6 MB
    uint16_t* Gb    = (uint16_t*)alloc((size_t)NN * HID * 2);// 12.8 MB
    float*    R     = (float*)alloc((size_t)NN * HID * 4);   // 25.6 MB
    // bpairs (NE*8B = 12.8MB) aliases H: dead before k_layer0 writes H
    int2*  bpairs = (int2*)H;
    // scalar aliases into Gb region (dead at those program points)
    float* agg0 = (float*)Gb;          // used before first k_pre3
    float* sarr = (float*)Gb;          // used after last k_aggrelu consumed Gb
    float* rarr = (float*)Gb + NN;

    hipMemsetAsync(bcnt, 0, (size_t)NBKT * 4, stream);

    // CSR build
    k_bhist<<<512, 256, 0, stream>>>(dstp, bcnt);
    k_bscan<<<1, 512, 0, stream>>>(bcnt, bbase, bcur, offs);
    k_bpart<<<NTILE, 256, 0, stream>>>(src, dstp, ew, bcur, bpairs);
    k_bcsr<<<NBKT, 256, 0, stream>>>(bbase, bpairs, offs, pairs);

    // layer 0 (1-channel input)
    k_agg_scalar<<<(NN + 255) / 256, 256, 0, stream>>>(offs, pairs, x, agg0);
    k_layer0<<<(NN * HID) / 256, 256, 0, stream>>>(agg0, x, Wrel0, brel0, Wroot0, H);

    // 3 middle layers
    for (int l = 0; l < 3; l++) {
        k_pre3<<<NPRE, 64, 0, stream>>>(
            H, Wrel_mid + (size_t)l * HID * HID,
            Wroot_mid + (size_t)l * HID * HID, brel_mid + (size_t)l * HID,
            (uint32_t*)Gb, R);
        k_aggrelu<<<(NN / 4 * 64) / 256, 256, 0, stream>>>(
            offs, pairs, (const uint32_t*)Gb, R, H);
    }

    // last layer: push WrelL through segment_sum -> scalar aggregation
    k_lastdot<<<(NN * HID + 255) / 256, 256, 0, stream>>>(H, WrelL, WrootL, sarr, rarr);
    k_last<<<(NN + 255) / 256, 256, 0, stream>>>(offs, pairs, sarr, rarr, brelL, out);
}

// Round 8
// 436.245 us; speedup vs baseline: 2.6741x; 2.6741x over previous
//
#include <hip/hip_runtime.h>
#include <stdint.h>

// GraphConv x5 on MI355X — round 8.
// Round 7's k_pre3 spilled h[64] to scratch (VGPR=64, FETCH 743MB) -> reverted.
// vs round 6: pre-transform done with MFMA (16x16x32 bf16) using hi/lo bf16
// splitting of H and W for near-fp32 accuracy:
//   G = Wrel*h   (then rounded bf16 for the gather)
//   R = Wroot*h + b  (fp32)
// via Ah*Bh + Al*Bh + Ah*Bl (error ~2^-17 rel). One wave per 16-node strip,
// K=64 -> 6 chained MFMAs per 16x16 tile, weights L1-hot. H stored as two
// bf16 planes (Hh,Hl) produced directly by the aggregation epilogue.

#define NN 100000
#define NE 1600000
#define HID 64
#define NBKT 391            // ceil(NN/256), bucket = dst >> 8
#define TILE 4096
#define EPT 16              // TILE / 256
#define NTILE ((NE + TILE - 1) / TILE)   // 391
#define NSTRIP (NN / 16)    // 6250 (exact)

typedef __attribute__((ext_vector_type(8))) short bf16x8;
typedef __attribute__((ext_vector_type(4))) float f32x4;

__device__ __forceinline__ uint32_t rne_bf16(float v) {
    uint32_t u = __float_as_uint(v);
    return (u + 0x7fffu + ((u >> 16) & 1u)) >> 16;
}

// ---------------- CSR build (unchanged from round 6) ----------------

__global__ __launch_bounds__(256) void k_bhist(const int* __restrict__ dst,
                                               int* __restrict__ bcnt) {
    __shared__ int h[NBKT];
    for (int t = threadIdx.x; t < NBKT; t += 256) h[t] = 0;
    __syncthreads();
    int stride = gridDim.x * blockDim.x;
    for (int e = blockIdx.x * blockDim.x + threadIdx.x; e < NE; e += stride)
        atomicAdd(&h[dst[e] >> 8], 1);
    __syncthreads();
    for (int t = threadIdx.x; t < NBKT; t += 256)
        if (h[t]) atomicAdd(&bcnt[t], h[t]);
}

__global__ void k_bscan(const int* __restrict__ bcnt, int* __restrict__ bbase,
                        int* __restrict__ bcur, int* __restrict__ offs) {
    __shared__ int tmp[512];
    int t = threadIdx.x;
    int v = (t < NBKT) ? bcnt[t] : 0;
    int acc = v;
    tmp[t] = v;
    __syncthreads();
    for (int off = 1; off < 512; off <<= 1) {
        int u = (t >= off) ? tmp[t - off] : 0;
        __syncthreads();
        acc += u;
        tmp[t] = acc;
        __syncthreads();
    }
    if (t < NBKT) {
        bbase[t] = acc - v;
        bcur[t]  = acc - v;
    }
    if (t == 0) { bbase[NBKT] = NE; offs[NN] = NE; }
}

__global__ __launch_bounds__(256) void k_bpart(const int* __restrict__ src,
                                               const int* __restrict__ dst,
                                               const float* __restrict__ w,
                                               int* __restrict__ bcur,
                                               int2* __restrict__ bpairs) {
    __shared__ int hcnt[NBKT];
    __shared__ int hbase[NBKT];
    int tile0 = blockIdx.x * TILE;
    for (int t = threadIdx.x; t < NBKT; t += 256) hcnt[t] = 0;
    __syncthreads();

    int   pk[EPT];
    int   bk[EPT];
    float wv[EPT];
    #pragma unroll
    for (int k = 0; k < EPT; k++) {
        int e = tile0 + threadIdx.x + k * 256;
        if (e < NE) {
            int d = dst[e];
            int b = d >> 8;
            pk[k] = (src[e] << 8) | (d & 255);
            wv[k] = w[e];
            bk[k] = b;
            atomicAdd(&hcnt[b], 1);
        } else {
            bk[k] = -1;
        }
    }
    __syncthreads();
    for (int t = threadIdx.x; t < NBKT; t += 256) {
        int c = hcnt[t];
        hbase[t] = c ? atomicAdd(&bcur[t], c) : 0;
        hcnt[t] = 0;
    }
    __syncthreads();
    #pragma unroll
    for (int k = 0; k < EPT; k++) {
        if (bk[k] >= 0) {
            int pos = hbase[bk[k]] + atomicAdd(&hcnt[bk[k]], 1);
            bpairs[pos] = make_int2(pk[k], __float_as_int(wv[k]));
        }
    }
}

__global__ __launch_bounds__(256) void k_bcsr(const int* __restrict__ bbase,
                                              const int2* __restrict__ bpairs,
                                              int* __restrict__ offs,
                                              int2* __restrict__ pairs) {
    __shared__ int cnt[256];
    __shared__ int scn[256];
    __shared__ int cur[256];
    int k = blockIdx.x, t = threadIdx.x;
    int b = bbase[k], e = bbase[k + 1];
    cnt[t] = 0;
    __syncthreads();
    for (int j = b + t; j < e; j += 256)
        atomicAdd(&cnt[bpairs[j].x & 255], 1);
    __syncthreads();
    int v = cnt[t], acc = v;
    scn[t] = v;
    __syncthreads();
    for (int off = 1; off < 256; off <<= 1) {
        int u = (t >= off) ? scn[t - off] : 0;
        __syncthreads();
        acc += u;
        tmp_label:;
        scn[t] = acc;
        __syncthreads();
    }
    int excl = acc - v;
    cur[t] = excl;
    int d = (k << 8) + t;
    if (d < NN) offs[d] = b + excl;
    __syncthreads();
    for (int j = b + t; j < e; j += 256) {
        int2 q = bpairs[j];
        int pos = b + atomicAdd(&cur[q.x & 255], 1);
        pairs[pos] = make_int2(q.x >> 8, q.y);
    }
}

// ---------------- weight hi/lo split ----------------
// WgH/WgL = bf16 hi/lo of Wrel_mid; WrH/WrL of Wroot_mid. [l][c][k], 3*4096.
__global__ __launch_bounds__(256) void k_wsplit(const float* __restrict__ Wrel_mid,
                                                const float* __restrict__ Wroot_mid,
                                                uint16_t* __restrict__ WgH,
                                                uint16_t* __restrict__ WgL,
                                                uint16_t* __restrict__ WrH,
                                                uint16_t* __restrict__ WrL) {
    int i = blockIdx.x * blockDim.x + threadIdx.x;
    if (i >= 3 * 4096) return;
    float a = Wrel_mid[i];
    uint32_t ah = rne_bf16(a);
    float al = a - __uint_as_float(ah << 16);
    WgH[i] = (uint16_t)ah;
    WgL[i] = (uint16_t)rne_bf16(al);
    float b = Wroot_mid[i];
    uint32_t bh = rne_bf16(b);
    float bl = b - __uint_as_float(bh << 16);
    WrH[i] = (uint16_t)bh;
    WrL[i] = (uint16_t)rne_bf16(bl);
}

// ---------------- layers ----------------

__global__ void k_agg_scalar(const int* __restrict__ offs, const int2* __restrict__ pairs,
                             const float* __restrict__ val, float* __restrict__ out) {
    int i = blockIdx.x * blockDim.x + threadIdx.x;
    if (i >= NN) return;
    float a0 = 0.f, a1 = 0.f;
    int b = offs[i], e = offs[i + 1];
    int j = b;
    for (; j + 2 <= e; j += 2) {
        int2 p0 = pairs[j], p1 = pairs[j + 1];
        a0 += __int_as_float(p0.y) * val[p0.x];
        a1 += __int_as_float(p1.y) * val[p1.x];
    }
    for (; j < e; j++) {
        int2 p = pairs[j];
        a0 += __int_as_float(p.y) * val[p.x];
    }
    out[i] = a0 + a1;
}

// h0 = relu(agg0*Wrel0 + brel0 + x*Wroot0), stored as bf16 hi/lo planes
__global__ void k_layer0(const float* __restrict__ agg0, const float* __restrict__ x,
                         const float* __restrict__ Wrel0, const float* __restrict__ brel0,
                         const float* __restrict__ Wroot0,
                         uint16_t* __restrict__ Hh, uint16_t* __restrict__ Hl) {
    int idx = blockIdx.x * blockDim.x + threadIdx.x;  // NN*64 exact
    int i = idx >> 6, c = idx & 63;
    float v = agg0[i] * Wrel0[c] + brel0[c] + x[i] * Wroot0[c];
    v = v > 0.f ? v : 0.f;
    uint32_t hi = rne_bf16(v);
    float lo = v - __uint_as_float(hi << 16);
    Hh[idx] = (uint16_t)hi;
    Hl[idx] = (uint16_t)rne_bf16(lo);
}

// MFMA pre-transform: one wave per 16-node strip.
//   G[node][oc] = bf16( Wrel * h )        (for the gather)
//   R[node][oc] = Wroot * h + brel  (fp32)
// A-frag: A[m=lane&15][k=quad*8+j] from Hh/Hl; B-frag: W[n=lane&15][k=quad*8+j]
// (B^T form); D: col=lane&15, row=quad*4+reg. 6 MFMAs/tile (hi/lo 3-term).
__global__ __launch_bounds__(256) void k_mfma_pre(
        const uint16_t* __restrict__ Hh, const uint16_t* __restrict__ Hl,
        const uint16_t* __restrict__ WgH, const uint16_t* __restrict__ WgL,
        const uint16_t* __restrict__ WrH, const uint16_t* __restrict__ WrL,
        const float* __restrict__ brel,
        uint16_t* __restrict__ Gb, float* __restrict__ R) {
    int wave = threadIdx.x >> 6;
    int lane = threadIdx.x & 63;
    int strip = blockIdx.x * 4 + wave;
    if (strip >= NSTRIP) return;
    int row = lane & 15;
    int quad = lane >> 4;
    int anode = strip * 16 + row;
    int kb = quad * 8;

    bf16x8 ah0 = *(const bf16x8*)&Hh[anode * 64 + kb];
    bf16x8 ah1 = *(const bf16x8*)&Hh[anode * 64 + 32 + kb];
    bf16x8 al0 = *(const bf16x8*)&Hl[anode * 64 + kb];
    bf16x8 al1 = *(const bf16x8*)&Hl[anode * 64 + 32 + kb];

    #pragma unroll
    for (int t = 0; t < 4; t++) {
        int oc = t * 16 + row;
        // ---- G role ----
        {
            bf16x8 bh0 = *(const bf16x8*)&WgH[oc * 64 + kb];
            bf16x8 bh1 = *(const bf16x8*)&WgH[oc * 64 + 32 + kb];
            bf16x8 bl0 = *(const bf16x8*)&WgL[oc * 64 + kb];
            bf16x8 bl1 = *(const bf16x8*)&WgL[oc * 64 + 32 + kb];
            f32x4 acc = {0.f, 0.f, 0.f, 0.f};
            acc = __builtin_amdgcn_mfma_f32_16x16x32_bf16(ah0, bh0, acc, 0, 0, 0);
            acc = __builtin_amdgcn_mfma_f32_16x16x32_bf16(ah1, bh1, acc, 0, 0, 0);
            acc = __builtin_amdgcn_mfma_f32_16x16x32_bf16(al0, bh0, acc, 0, 0, 0);
            acc = __builtin_amdgcn_mfma_f32_16x16x32_bf16(al1, bh1, acc, 0, 0, 0);
            acc = __builtin_amdgcn_mfma_f32_16x16x32_bf16(ah0, bl0, acc, 0, 0, 0);
            acc = __builtin_amdgcn_mfma_f32_16x16x32_bf16(ah1, bl1, acc, 0, 0, 0);
            #pragma unroll
            for (int r = 0; r < 4; r++) {
                int nd = strip * 16 + quad * 4 + r;
                Gb[nd * 64 + t * 16 + row] = (uint16_t)rne_bf16(acc[r]);
            }
        }
        // ---- R role ----
        {
            bf16x8 bh0 = *(const bf16x8*)&WrH[oc * 64 + kb];
            bf16x8 bh1 = *(const bf16x8*)&WrH[oc * 64 + 32 + kb];
            bf16x8 bl0 = *(const bf16x8*)&WrL[oc * 64 + kb];
            bf16x8 bl1 = *(const bf16x8*)&WrL[oc * 64 + 32 + kb];
            float bias = brel[t * 16 + row];
            f32x4 acc = {bias, bias, bias, bias};
            acc = __builtin_amdgcn_mfma_f32_16x16x32_bf16(ah0, bh0, acc, 0, 0, 0);
            acc = __builtin_amdgcn_mfma_f32_16x16x32_bf16(ah1, bh1, acc, 0, 0, 0);
            acc = __builtin_amdgcn_mfma_f32_16x16x32_bf16(al0, bh0, acc, 0, 0, 0);
            acc = __builtin_amdgcn_mfma_f32_16x16x32_bf16(al1, bh1, acc, 0, 0, 0);
            acc = __builtin_amdgcn_mfma_f32_16x16x32_bf16(ah0, bl0, acc, 0, 0, 0);
            acc = __builtin_amdgcn_mfma_f32_16x16x32_bf16(ah1, bl1, acc, 0, 0, 0);
            #pragma unroll
            for (int r = 0; r < 4; r++) {
                int nd = strip * 16 + quad * 4 + r;
                R[nd * 64 + t * 16 + row] = acc[r];
            }
        }
    }
}

// hout = relu( sum_j w_j*G[src_j] + R[i] ), G bf16 [node][c] (128B rows).
// Output written as bf16 hi/lo planes for the next layer's MFMA.
__global__ __launch_bounds__(256) void k_aggrelu(
        const int* __restrict__ offs, const int2* __restrict__ pairs,
        const uint16_t* __restrict__ Gb, const float* __restrict__ R,
        uint16_t* __restrict__ Hh, uint16_t* __restrict__ Hl) {
    int c = threadIdx.x & 63;
    int wid = (blockIdx.x * blockDim.x + threadIdx.x) >> 6;
    int n0 = wid << 2;                // NN % 4 == 0
    if (n0 >= NN) return;
    int ov = (c < 5) ? offs[n0 + c] : 0;
    int bnd[5];
    bnd[0] = __builtin_amdgcn_readlane(ov, 0);
    bnd[1] = __builtin_amdgcn_readlane(ov, 1);
    bnd[2] = __builtin_amdgcn_readlane(ov, 2);
    bnd[3] = __builtin_amdgcn_readlane(ov, 3);
    bnd[4] = __builtin_amdgcn_readlane(ov, 4);

    float accA[4] = {0.f, 0.f, 0.f, 0.f};
    float accB[4] = {0.f, 0.f, 0.f, 0.f};

    for (int cb = bnd[0]; cb < bnd[4]; cb += 64) {
        int n = bnd[4] - cb; if (n > 64) n = 64;
        int2 p = (c < n) ? pairs[cb + c] : make_int2(0, 0);
        #pragma unroll
        for (int t = 0; t < 4; t++) {
            int lo = bnd[t]     > cb     ? bnd[t]     : cb;
            int hi = bnd[t + 1] < cb + n ? bnd[t + 1] : cb + n;
            int j = lo;
            for (; j + 4 <= hi; j += 4) {
                int jj = j - cb;
                int s0 = __builtin_amdgcn_readlane(p.x, jj + 0);
                int s1 = __builtin_amdgcn_readlane(p.x, jj + 1);
                int s2 = __builtin_amdgcn_readlane(p.x, jj + 2);
                int s3 = __builtin_amdgcn_readlane(p.x, jj + 3);
                float w0 = __uint_as_float(__builtin_amdgcn_readlane(p.y, jj + 0));
                float w1 = __uint_as_float(__builtin_amdgcn_readlane(p.y, jj + 1));
                float w2 = __uint_as_float(__builtin_amdgcn_readlane(p.y, jj + 2));
                float w3 = __uint_as_float(__builtin_amdgcn_readlane(p.y, jj + 3));
                uint32_t u0 = Gb[s0 * 64 + c];
                uint32_t u1 = Gb[s1 * 64 + c];
                uint32_t u2 = Gb[s2 * 64 + c];
                uint32_t u3 = Gb[s3 * 64 + c];
                accA[t] += w0 * __uint_as_float(u0 << 16);
                accB[t] += w1 * __uint_as_float(u1 << 16);
                accA[t] += w2 * __uint_as_float(u2 << 16);
                accB[t] += w3 * __uint_as_float(u3 << 16);
            }
            for (; j < hi; j++) {
                int jj = j - cb;
                int s = __builtin_amdgcn_readlane(p.x, jj);
                float wv = __uint_as_float(__builtin_amdgcn_readlane(p.y, jj));
                uint32_t u = Gb[s * 64 + c];
                accA[t] += wv * __uint_as_float(u << 16);
            }
        }
    }
    #pragma unroll
    for (int t = 0; t < 4; t++) {
        float v = accA[t] + accB[t] + R[(n0 + t) * 64 + c];
        v = v > 0.f ? v : 0.f;
        uint32_t hi = rne_bf16(v);
        float lo = v - __uint_as_float(hi << 16);
        Hh[(n0 + t) * 64 + c] = (uint16_t)hi;
        Hl[(n0 + t) * 64 + c] = (uint16_t)rne_bf16(lo);
    }
}

__global__ void k_lastdot(const uint16_t* __restrict__ Hh, const uint16_t* __restrict__ Hl,
                          const float* __restrict__ WrelL, const float* __restrict__ WrootL,
                          float* __restrict__ sarr, float* __restrict__ rarr) {
    int g = blockIdx.x * blockDim.x + threadIdx.x;
    int node = g >> 6, lane = g & 63;
    if (node >= NN) return;
    uint32_t uh = Hh[node * 64 + lane], ul = Hl[node * 64 + lane];
    float v = __uint_as_float(uh << 16) + __uint_as_float(ul << 16);
    float a = v * WrelL[lane];
    float c = v * WrootL[lane];
    for (int o = 32; o > 0; o >>= 1) {
        a += __shfl_down(a, o, 64);
        c += __shfl_down(c, o, 64);
    }
    if (lane == 0) { sarr[node] = a; rarr[node] = c; }
}

__global__ void k_last(const int* __restrict__ offs, const int2* __restrict__ pairs,
                       const float* __restrict__ sarr, const float* __restrict__ rarr,
                       const float* __restrict__ brelL, float* __restrict__ out) {
    int i = blockIdx.x * blockDim.x + threadIdx.x;
    if (i >= NN) return;
    float a0 = rarr[i] + brelL[0], a1 = 0.f;
    int b = offs[i], e = offs[i + 1];
    int j = b;
    for (; j + 2 <= e; j += 2) {
        int2 p0 = pairs[j], p1 = pairs[j + 1];
        a0 += __int_as_float(p0.y) * sarr[p0.x];
        a1 += __int_as_float(p1.y) * sarr[p1.x];
    }
    for (; j < e; j++) {
        int2 p = pairs[j];
        a0 += __int_as_float(p.y) * sarr[p.x];
    }
    out[i] = a0 + a1;
}

extern "C" void kernel_launch(void* const* d_in, const int* in_sizes, int n_in,
                              void* d_out, int out_size, void* d_ws, size_t ws_size,
                              hipStream_t stream) {
    const float* x        = (const float*)d_in[0];
    const int*   ei       = (const int*)d_in[1];
    const float* ew       = (const float*)d_in[2];
    const float* Wrel0    = (const float*)d_in[3];
    const float* brel0    = (const float*)d_in[4];
    const float* Wroot0   = (const float*)d_in[5];
    const float* Wrel_mid = (const float*)d_in[6];
    const float* brel_mid = (const float*)d_in[7];
    const float* Wroot_mid= (const float*)d_in[8];
    const float* WrelL    = (const float*)d_in[9];
    const float* brelL    = (const float*)d_in[10];
    const float* WrootL   = (const float*)d_in[11];
    float* out = (float*)d_out;

    const int* src  = ei;
    const int* dstp = ei + NE;

    char* w = (char*)d_ws;
    size_t o = 0;
    auto alloc = [&](size_t b) -> void* {
        void* r = (void*)(w + o);
        o += (b + 255) & ~(size_t)255;
        return r;
    };
    int*      offs  = (int*)alloc((size_t)(NN + 1) * 4);
    int*      bcnt  = (int*)alloc((size_t)NBKT * 4);
    int*      bbase = (int*)alloc((size_t)(NBKT + 1) * 4);
    int*      bcur  = (int*)alloc((size_t)NBKT * 4);
    uint16_t* WgH   = (uint16_t*)alloc((size_t)3 * 4096 * 2);
    uint16_t* WgL   = (uint16_t*)alloc((size_t)3 * 4096 * 2);
    uint16_t* WrH   = (uint16_t*)alloc((size_t)3 * 4096 * 2);
    uint16_t* WrL   = (uint16_t*)alloc((size_t)3 * 4096 * 2);
    int2*     pairs = (int2*)alloc((size_t)NE * 8);
    uint16_t* Hh    = (uint16_t*)alloc((size_t)NN * HID * 2); // 12.8 MB
    uint16_t* Hl    = (uint16_t*)alloc((size_t)NN * HID * 2); // 12.8 MB
    uint16_t* Gb    = (uint16_t*)alloc((size_t)NN * HID * 2); // 12.8 MB
    float*    R     = (float*)alloc((size_t)NN * HID * 4);    // 25.6 MB
    // bpairs (NE*8B = 12.8MB) aliases Hh: dead before k_layer0 writes Hh
    int2*  bpairs = (int2*)Hh;
    // scalar aliases into Gb region (dead at those program points)
    float* agg0 = (float*)Gb;          // used before first k_mfma_pre
    float* sarr = (float*)Gb;          // used after last k_aggrelu consumed Gb
    float* rarr = (float*)Gb + NN;

    hipMemsetAsync(bcnt, 0, (size_t)NBKT * 4, stream);

    // CSR build
    k_bhist<<<512, 256, 0, stream>>>(dstp, bcnt);
    k_bscan<<<1, 512, 0, stream>>>(bcnt, bbase, bcur, offs);
    k_bpart<<<NTILE, 256, 0, stream>>>(src, dstp, ew, bcur, bpairs);
    k_bcsr<<<NBKT, 256, 0, stream>>>(bbase, bpairs, offs, pairs);

    // weight hi/lo split (all 3 mid layers, both roles)
    k_wsplit<<<(3 * 4096 + 255) / 256, 256, 0, stream>>>(
        Wrel_mid, Wroot_mid, WgH, WgL, WrH, WrL);

    // layer 0 (1-channel input)
    k_agg_scalar<<<(NN + 255) / 256, 256, 0, stream>>>(offs, pairs, x, agg0);
    k_layer0<<<(NN * HID) / 256, 256, 0, stream>>>(agg0, x, Wrel0, brel0, Wroot0, Hh, Hl);

    // 3 middle layers
    for (int l = 0; l < 3; l++) {
        k_mfma_pre<<<(NSTRIP + 3) / 4, 256, 0, stream>>>(
            Hh, Hl,
            WgH + (size_t)l * 4096, WgL + (size_t)l * 4096,
            WrH + (size_t)l * 4096, WrL + (size_t)l * 4096,
            brel_mid + (size_t)l * HID, Gb, R);
        k_aggrelu<<<(NN / 4 * 64) / 256, 256, 0, stream>>>(
            offs, pairs, Gb, R, Hh, Hl);
    }

    // last layer: push WrelL through segment_sum -> scalar aggregation
    k_lastdot<<<(NN * HID + 255) / 256, 256, 0, stream>>>(Hh, Hl, WrelL, WrootL, sarr, rarr);
    k_last<<<(NN + 255) / 256, 256, 0, stream>>>(offs, pairs, sarr, rarr, brelL, out);
}

// Round 9
// 435.141 us; speedup vs baseline: 2.6809x; 1.0025x over previous
//
#include <hip/hip_runtime.h>
#include <stdint.h>

// GraphConv x5 on MI355X — round 9.
// vs round 8:
// (1) k_aggrelu restructured: ONE wave per node, all metadata wave-uniform ->
//     offs/pairs load through the SCALAR pipe (s_load), weight is the SGPR
//     operand of v_fmac. Per-edge VALU: gather + shl16 + fmac (was ~10 with
//     readlanes + 4-segment masked routing). Unroll 8 = 8 gathers in flight.
// (2) k_lastdot fused into the last aggrelu's epilogue (wave reduction),
//     saving a 51MB H round-trip + a launch. sarr/rarr de-aliased from Gb.

#define NN 100000
#define NE 1600000
#define HID 64
#define NBKT 391            // ceil(NN/256), bucket = dst >> 8
#define TILE 4096
#define EPT 16              // TILE / 256
#define NTILE ((NE + TILE - 1) / TILE)   // 391
#define NSTRIP (NN / 16)    // 6250 (exact)

typedef __attribute__((ext_vector_type(8))) short bf16x8;
typedef __attribute__((ext_vector_type(4))) float f32x4;

__device__ __forceinline__ uint32_t rne_bf16(float v) {
    uint32_t u = __float_as_uint(v);
    return (u + 0x7fffu + ((u >> 16) & 1u)) >> 16;
}

// ---------------- CSR build ----------------

__global__ __launch_bounds__(256) void k_bhist(const int* __restrict__ dst,
                                               int* __restrict__ bcnt) {
    __shared__ int h[NBKT];
    for (int t = threadIdx.x; t < NBKT; t += 256) h[t] = 0;
    __syncthreads();
    int stride = gridDim.x * blockDim.x;
    for (int e = blockIdx.x * blockDim.x + threadIdx.x; e < NE; e += stride)
        atomicAdd(&h[dst[e] >> 8], 1);
    __syncthreads();
    for (int t = threadIdx.x; t < NBKT; t += 256)
        if (h[t]) atomicAdd(&bcnt[t], h[t]);
}

__global__ void k_bscan(const int* __restrict__ bcnt, int* __restrict__ bbase,
                        int* __restrict__ bcur, int* __restrict__ offs) {
    __shared__ int tmp[512];
    int t = threadIdx.x;
    int v = (t < NBKT) ? bcnt[t] : 0;
    int acc = v;
    tmp[t] = v;
    __syncthreads();
    for (int off = 1; off < 512; off <<= 1) {
        int u = (t >= off) ? tmp[t - off] : 0;
        __syncthreads();
        acc += u;
        tmp[t] = acc;
        __syncthreads();
    }
    if (t < NBKT) {
        bbase[t] = acc - v;
        bcur[t]  = acc - v;
    }
    if (t == 0) { bbase[NBKT] = NE; offs[NN] = NE; }
}

__global__ __launch_bounds__(256) void k_bpart(const int* __restrict__ src,
                                               const int* __restrict__ dst,
                                               const float* __restrict__ w,
                                               int* __restrict__ bcur,
                                               int2* __restrict__ bpairs) {
    __shared__ int hcnt[NBKT];
    __shared__ int hbase[NBKT];
    int tile0 = blockIdx.x * TILE;
    for (int t = threadIdx.x; t < NBKT; t += 256) hcnt[t] = 0;
    __syncthreads();

    int   pk[EPT];
    int   bk[EPT];
    float wv[EPT];
    #pragma unroll
    for (int k = 0; k < EPT; k++) {
        int e = tile0 + threadIdx.x + k * 256;
        if (e < NE) {
            int d = dst[e];
            int b = d >> 8;
            pk[k] = (src[e] << 8) | (d & 255);
            wv[k] = w[e];
            bk[k] = b;
            atomicAdd(&hcnt[b], 1);
        } else {
            bk[k] = -1;
        }
    }
    __syncthreads();
    for (int t = threadIdx.x; t < NBKT; t += 256) {
        int c = hcnt[t];
        hbase[t] = c ? atomicAdd(&bcur[t], c) : 0;
        hcnt[t] = 0;
    }
    __syncthreads();
    #pragma unroll
    for (int k = 0; k < EPT; k++) {
        if (bk[k] >= 0) {
            int pos = hbase[bk[k]] + atomicAdd(&hcnt[bk[k]], 1);
            bpairs[pos] = make_int2(pk[k], __float_as_int(wv[k]));
        }
    }
}

__global__ __launch_bounds__(256) void k_bcsr(const int* __restrict__ bbase,
                                              const int2* __restrict__ bpairs,
                                              int* __restrict__ offs,
                                              int2* __restrict__ pairs) {
    __shared__ int cnt[256];
    __shared__ int scn[256];
    __shared__ int cur[256];
    int k = blockIdx.x, t = threadIdx.x;
    int b = bbase[k], e = bbase[k + 1];
    cnt[t] = 0;
    __syncthreads();
    for (int j = b + t; j < e; j += 256)
        atomicAdd(&cnt[bpairs[j].x & 255], 1);
    __syncthreads();
    int v = cnt[t], acc = v;
    scn[t] = v;
    __syncthreads();
    for (int off = 1; off < 256; off <<= 1) {
        int u = (t >= off) ? scn[t - off] : 0;
        __syncthreads();
        acc += u;
        scn[t] = acc;
        __syncthreads();
    }
    int excl = acc - v;
    cur[t] = excl;
    int d = (k << 8) + t;
    if (d < NN) offs[d] = b + excl;
    __syncthreads();
    for (int j = b + t; j < e; j += 256) {
        int2 q = bpairs[j];
        int pos = b + atomicAdd(&cur[q.x & 255], 1);
        pairs[pos] = make_int2(q.x >> 8, q.y);
    }
}

// ---------------- weight hi/lo split ----------------

__global__ __launch_bounds__(256) void k_wsplit(const float* __restrict__ Wrel_mid,
                                                const float* __restrict__ Wroot_mid,
                                                uint16_t* __restrict__ WgH,
                                                uint16_t* __restrict__ WgL,
                                                uint16_t* __restrict__ WrH,
                                                uint16_t* __restrict__ WrL) {
    int i = blockIdx.x * blockDim.x + threadIdx.x;
    if (i >= 3 * 4096) return;
    float a = Wrel_mid[i];
    uint32_t ah = rne_bf16(a);
    float al = a - __uint_as_float(ah << 16);
    WgH[i] = (uint16_t)ah;
    WgL[i] = (uint16_t)rne_bf16(al);
    float b = Wroot_mid[i];
    uint32_t bh = rne_bf16(b);
    float bl = b - __uint_as_float(bh << 16);
    WrH[i] = (uint16_t)bh;
    WrL[i] = (uint16_t)rne_bf16(bl);
}

// ---------------- layers ----------------

__global__ void k_agg_scalar(const int* __restrict__ offs, const int2* __restrict__ pairs,
                             const float* __restrict__ val, float* __restrict__ out) {
    int i = blockIdx.x * blockDim.x + threadIdx.x;
    if (i >= NN) return;
    float a0 = 0.f, a1 = 0.f;
    int b = offs[i], e = offs[i + 1];
    int j = b;
    for (; j + 2 <= e; j += 2) {
        int2 p0 = pairs[j], p1 = pairs[j + 1];
        a0 += __int_as_float(p0.y) * val[p0.x];
        a1 += __int_as_float(p1.y) * val[p1.x];
    }
    for (; j < e; j++) {
        int2 p = pairs[j];
        a0 += __int_as_float(p.y) * val[p.x];
    }
    out[i] = a0 + a1;
}

__global__ void k_layer0(const float* __restrict__ agg0, const float* __restrict__ x,
                         const float* __restrict__ Wrel0, const float* __restrict__ brel0,
                         const float* __restrict__ Wroot0,
                         uint16_t* __restrict__ Hh, uint16_t* __restrict__ Hl) {
    int idx = blockIdx.x * blockDim.x + threadIdx.x;  // NN*64 exact
    int i = idx >> 6, c = idx & 63;
    float v = agg0[i] * Wrel0[c] + brel0[c] + x[i] * Wroot0[c];
    v = v > 0.f ? v : 0.f;
    uint32_t hi = rne_bf16(v);
    float lo = v - __uint_as_float(hi << 16);
    Hh[idx] = (uint16_t)hi;
    Hl[idx] = (uint16_t)rne_bf16(lo);
}

// MFMA pre-transform (unchanged from round 8; validated absmax=16).
__global__ __launch_bounds__(256) void k_mfma_pre(
        const uint16_t* __restrict__ Hh, const uint16_t* __restrict__ Hl,
        const uint16_t* __restrict__ WgH, const uint16_t* __restrict__ WgL,
        const uint16_t* __restrict__ WrH, const uint16_t* __restrict__ WrL,
        const float* __restrict__ brel,
        uint16_t* __restrict__ Gb, float* __restrict__ R) {
    int wave = threadIdx.x >> 6;
    int lane = threadIdx.x & 63;
    int strip = blockIdx.x * 4 + wave;
    if (strip >= NSTRIP) return;
    int row = lane & 15;
    int quad = lane >> 4;
    int anode = strip * 16 + row;
    int kb = quad * 8;

    bf16x8 ah0 = *(const bf16x8*)&Hh[anode * 64 + kb];
    bf16x8 ah1 = *(const bf16x8*)&Hh[anode * 64 + 32 + kb];
    bf16x8 al0 = *(const bf16x8*)&Hl[anode * 64 + kb];
    bf16x8 al1 = *(const bf16x8*)&Hl[anode * 64 + 32 + kb];

    #pragma unroll
    for (int t = 0; t < 4; t++) {
        int oc = t * 16 + row;
        {
            bf16x8 bh0 = *(const bf16x8*)&WgH[oc * 64 + kb];
            bf16x8 bh1 = *(const bf16x8*)&WgH[oc * 64 + 32 + kb];
            bf16x8 bl0 = *(const bf16x8*)&WgL[oc * 64 + kb];
            bf16x8 bl1 = *(const bf16x8*)&WgL[oc * 64 + 32 + kb];
            f32x4 acc = {0.f, 0.f, 0.f, 0.f};
            acc = __builtin_amdgcn_mfma_f32_16x16x32_bf16(ah0, bh0, acc, 0, 0, 0);
            acc = __builtin_amdgcn_mfma_f32_16x16x32_bf16(ah1, bh1, acc, 0, 0, 0);
            acc = __builtin_amdgcn_mfma_f32_16x16x32_bf16(al0, bh0, acc, 0, 0, 0);
            acc = __builtin_amdgcn_mfma_f32_16x16x32_bf16(al1, bh1, acc, 0, 0, 0);
            acc = __builtin_amdgcn_mfma_f32_16x16x32_bf16(ah0, bl0, acc, 0, 0, 0);
            acc = __builtin_amdgcn_mfma_f32_16x16x32_bf16(ah1, bl1, acc, 0, 0, 0);
            #pragma unroll
            for (int r = 0; r < 4; r++) {
                int nd = strip * 16 + quad * 4 + r;
                Gb[nd * 64 + t * 16 + row] = (uint16_t)rne_bf16(acc[r]);
            }
        }
        {
            bf16x8 bh0 = *(const bf16x8*)&WrH[oc * 64 + kb];
            bf16x8 bh1 = *(const bf16x8*)&WrH[oc * 64 + 32 + kb];
            bf16x8 bl0 = *(const bf16x8*)&WrL[oc * 64 + kb];
            bf16x8 bl1 = *(const bf16x8*)&WrL[oc * 64 + 32 + kb];
            float bias = brel[t * 16 + row];
            f32x4 acc = {bias, bias, bias, bias};
            acc = __builtin_amdgcn_mfma_f32_16x16x32_bf16(ah0, bh0, acc, 0, 0, 0);
            acc = __builtin_amdgcn_mfma_f32_16x16x32_bf16(ah1, bh1, acc, 0, 0, 0);
            acc = __builtin_amdgcn_mfma_f32_16x16x32_bf16(al0, bh0, acc, 0, 0, 0);
            acc = __builtin_amdgcn_mfma_f32_16x16x32_bf16(al1, bh1, acc, 0, 0, 0);
            acc = __builtin_amdgcn_mfma_f32_16x16x32_bf16(ah0, bl0, acc, 0, 0, 0);
            acc = __builtin_amdgcn_mfma_f32_16x16x32_bf16(ah1, bl1, acc, 0, 0, 0);
            #pragma unroll
            for (int r = 0; r < 4; r++) {
                int nd = strip * 16 + quad * 4 + r;
                R[nd * 64 + t * 16 + row] = acc[r];
            }
        }
    }
}

// Aggregation: ONE wave per node; metadata wave-uniform (scalar pipe).
// hout = relu( sum_j w_j*G[src_j] + R[i] ). LAST: wave-reduce s,r instead
// of storing H planes.
template <bool LAST>
__global__ __launch_bounds__(256) void k_aggrelu2(
        const int* __restrict__ offs, const int2* __restrict__ pairs,
        const uint16_t* __restrict__ Gb, const float* __restrict__ R,
        uint16_t* __restrict__ Hh, uint16_t* __restrict__ Hl,
        const float* __restrict__ WrelL, const float* __restrict__ WrootL,
        float* __restrict__ sarr, float* __restrict__ rarr) {
    int c = threadIdx.x & 63;
    int node = __builtin_amdgcn_readfirstlane(blockIdx.x * 4 + (threadIdx.x >> 6));
    // grid is exactly NN/4 blocks; NN % 4 == 0 -> node < NN always
    int b = __builtin_amdgcn_readfirstlane(offs[node]);
    int e = __builtin_amdgcn_readfirstlane(offs[node + 1]);

    float a0 = 0.f, a1 = 0.f, a2 = 0.f, a3 = 0.f;
    float a4 = 0.f, a5 = 0.f, a6 = 0.f, a7 = 0.f;
    int j = b;
    for (; j + 8 <= e; j += 8) {
        int s0 = __builtin_amdgcn_readfirstlane(pairs[j + 0].x);
        int w0 = __builtin_amdgcn_readfirstlane(pairs[j + 0].y);
        int s1 = __builtin_amdgcn_readfirstlane(pairs[j + 1].x);
        int w1 = __builtin_amdgcn_readfirstlane(pairs[j + 1].y);
        int s2 = __builtin_amdgcn_readfirstlane(pairs[j + 2].x);
        int w2 = __builtin_amdgcn_readfirstlane(pairs[j + 2].y);
        int s3 = __builtin_amdgcn_readfirstlane(pairs[j + 3].x);
        int w3 = __builtin_amdgcn_readfirstlane(pairs[j + 3].y);
        int s4 = __builtin_amdgcn_readfirstlane(pairs[j + 4].x);
        int w4 = __builtin_amdgcn_readfirstlane(pairs[j + 4].y);
        int s5 = __builtin_amdgcn_readfirstlane(pairs[j + 5].x);
        int w5 = __builtin_amdgcn_readfirstlane(pairs[j + 5].y);
        int s6 = __builtin_amdgcn_readfirstlane(pairs[j + 6].x);
        int w6 = __builtin_amdgcn_readfirstlane(pairs[j + 6].y);
        int s7 = __builtin_amdgcn_readfirstlane(pairs[j + 7].x);
        int w7 = __builtin_amdgcn_readfirstlane(pairs[j + 7].y);
        uint32_t u0 = Gb[s0 * 64 + c];
        uint32_t u1 = Gb[s1 * 64 + c];
        uint32_t u2 = Gb[s2 * 64 + c];
        uint32_t u3 = Gb[s3 * 64 + c];
        uint32_t u4 = Gb[s4 * 64 + c];
        uint32_t u5 = Gb[s5 * 64 + c];
        uint32_t u6 = Gb[s6 * 64 + c];
        uint32_t u7 = Gb[s7 * 64 + c];
        a0 += __int_as_float(w0) * __uint_as_float(u0 << 16);
        a1 += __int_as_float(w1) * __uint_as_float(u1 << 16);
        a2 += __int_as_float(w2) * __uint_as_float(u2 << 16);
        a3 += __int_as_float(w3) * __uint_as_float(u3 << 16);
        a4 += __int_as_float(w4) * __uint_as_float(u4 << 16);
        a5 += __int_as_float(w5) * __uint_as_float(u5 << 16);
        a6 += __int_as_float(w6) * __uint_as_float(u6 << 16);
        a7 += __int_as_float(w7) * __uint_as_float(u7 << 16);
    }
    for (; j < e; j++) {
        int s = __builtin_amdgcn_readfirstlane(pairs[j].x);
        int w = __builtin_amdgcn_readfirstlane(pairs[j].y);
        uint32_t u = Gb[s * 64 + c];
        a0 += __int_as_float(w) * __uint_as_float(u << 16);
    }
    float v = ((a0 + a1) + (a2 + a3)) + ((a4 + a5) + (a6 + a7)) + R[node * 64 + c];
    v = v > 0.f ? v : 0.f;
    if (!LAST) {
        uint32_t hi = rne_bf16(v);
        float lo = v - __uint_as_float(hi << 16);
        Hh[node * 64 + c] = (uint16_t)hi;
        Hl[node * 64 + c] = (uint16_t)rne_bf16(lo);
    } else {
        float a = v * WrelL[c];
        float r = v * WrootL[c];
        for (int o = 32; o > 0; o >>= 1) {
            a += __shfl_down(a, o, 64);
            r += __shfl_down(r, o, 64);
        }
        if (c == 0) { sarr[node] = a; rarr[node] = r; }
    }
}

__global__ void k_last(const int* __restrict__ offs, const int2* __restrict__ pairs,
                       const float* __restrict__ sarr, const float* __restrict__ rarr,
                       const float* __restrict__ brelL, float* __restrict__ out) {
    int i = blockIdx.x * blockDim.x + threadIdx.x;
    if (i >= NN) return;
    float a0 = rarr[i] + brelL[0], a1 = 0.f;
    int b = offs[i], e = offs[i + 1];
    int j = b;
    for (; j + 2 <= e; j += 2) {
        int2 p0 = pairs[j], p1 = pairs[j + 1];
        a0 += __int_as_float(p0.y) * sarr[p0.x];
        a1 += __int_as_float(p1.y) * sarr[p1.x];
    }
    for (; j < e; j++) {
        int2 p = pairs[j];
        a0 += __int_as_float(p.y) * sarr[p.x];
    }
    out[i] = a0 + a1;
}

extern "C" void kernel_launch(void* const* d_in, const int* in_sizes, int n_in,
                              void* d_out, int out_size, void* d_ws, size_t ws_size,
                              hipStream_t stream) {
    const float* x        = (const float*)d_in[0];
    const int*   ei       = (const int*)d_in[1];
    const float* ew       = (const float*)d_in[2];
    const float* Wrel0    = (const float*)d_in[3];
    const float* brel0    = (const float*)d_in[4];
    const float* Wroot0   = (const float*)d_in[5];
    const float* Wrel_mid = (const float*)d_in[6];
    const float* brel_mid = (const float*)d_in[7];
    const float* Wroot_mid= (const float*)d_in[8];
    const float* WrelL    = (const float*)d_in[9];
    const float* brelL    = (const float*)d_in[10];
    const float* WrootL   = (const float*)d_in[11];
    float* out = (float*)d_out;

    const int* src  = ei;
    const int* dstp = ei + NE;

    char* w = (char*)d_ws;
    size_t o = 0;
    auto alloc = [&](size_t b) -> void* {
        void* r = (void*)(w + o);
        o += (b + 255) & ~(size_t)255;
        return r;
    };
    int*      offs  = (int*)alloc((size_t)(NN + 1) * 4);
    int*      bcnt  = (int*)alloc((size_t)NBKT * 4);
    int*      bbase = (int*)alloc((size_t)(NBKT + 1) * 4);
    int*      bcur  = (int*)alloc((size_t)NBKT * 4);
    uint16_t* WgH   = (uint16_t*)alloc((size_t)3 * 4096 * 2);
    uint16_t* WgL   = (uint16_t*)alloc((size_t)3 * 4096 * 2);
    uint16_t* WrH   = (uint16_t*)alloc((size_t)3 * 4096 * 2);
    uint16_t* WrL   = (uint16_t*)alloc((size_t)3 * 4096 * 2);
    float*    sarr  = (float*)alloc((size_t)NN * 4);
    float*    rarr  = (float*)alloc((size_t)NN * 4);
    int2*     pairs = (int2*)alloc((size_t)NE * 8);
    uint16_t* Hh    = (uint16_t*)alloc((size_t)NN * HID * 2); // 12.8 MB
    uint16_t* Hl    = (uint16_t*)alloc((size_t)NN * HID * 2); // 12.8 MB
    uint16_t* Gb    = (uint16_t*)alloc((size_t)NN * HID * 2); // 12.8 MB
    float*    R     = (float*)alloc((size_t)NN * HID * 4);    // 25.6 MB
    // bpairs (NE*8B = 12.8MB) aliases Hh: dead before k_layer0 writes Hh
    int2*  bpairs = (int2*)Hh;
    // agg0 aliases Gb (dead before first k_mfma_pre writes Gb)
    float* agg0 = (float*)Gb;

    hipMemsetAsync(bcnt, 0, (size_t)NBKT * 4, stream);

    // CSR build
    k_bhist<<<512, 256, 0, stream>>>(dstp, bcnt);
    k_bscan<<<1, 512, 0, stream>>>(bcnt, bbase, bcur, offs);
    k_bpart<<<NTILE, 256, 0, stream>>>(src, dstp, ew, bcur, bpairs);
    k_bcsr<<<NBKT, 256, 0, stream>>>(bbase, bpairs, offs, pairs);

    // weight hi/lo split
    k_wsplit<<<(3 * 4096 + 255) / 256, 256, 0, stream>>>(
        Wrel_mid, Wroot_mid, WgH, WgL, WrH, WrL);

    // layer 0 (1-channel input)
    k_agg_scalar<<<(NN + 255) / 256, 256, 0, stream>>>(offs, pairs, x, agg0);
    k_layer0<<<(NN * HID) / 256, 256, 0, stream>>>(agg0, x, Wrel0, brel0, Wroot0, Hh, Hl);

    // 3 middle layers; last one fuses the final dot-products into its epilogue
    for (int l = 0; l < 3; l++) {
        k_mfma_pre<<<(NSTRIP + 3) / 4, 256, 0, stream>>>(
            Hh, Hl,
            WgH + (size_t)l * 4096, WgL + (size_t)l * 4096,
            WrH + (size_t)l * 4096, WrL + (size_t)l * 4096,
            brel_mid + (size_t)l * HID, Gb, R);
        if (l < 2) {
            k_aggrelu2<false><<<NN / 4, 256, 0, stream>>>(
                offs, pairs, Gb, R, Hh, Hl, WrelL, WrootL, sarr, rarr);
        } else {
            k_aggrelu2<true><<<NN / 4, 256, 0, stream>>>(
                offs, pairs, Gb, R, Hh, Hl, WrelL, WrootL, sarr, rarr);
        }
    }

    // final edge pass on scalars
    k_last<<<(NN + 255) / 256, 256, 0, stream>>>(offs, pairs, sarr, rarr, brelL, out);
}

// Round 10
// 417.733 us; speedup vs baseline: 2.7926x; 1.0417x over previous
//
#include <hip/hip_runtime.h>
#include <stdint.h>

// GraphConv x5 on MI355X — round 10.
// vs round 9: (1) aggregation reverted to the round-8 structure (4 adjacent
// nodes/wave, ONE cooperative 512B metadata window load, segmented per-node
// scalar-bound loops w/ readlane) — round-9's wave-per-node serialized s_load
// chains on ~16-edge loops and regressed 47->54us. Fused last-layer reduction
// kept. (2) The aggregation kernel is beyond-L2-fetch bound (~100MB @
// ~2.5TB/s), so cut bytes on that path: R stored bf16 (25.6->12.8MB) and H
// stored as a single bf16 plane (write 25.6->12.8MB; mfma_pre reads half).
// mfma_pre: 4 MFMAs/tile (W hi/lo kept; H single-plane).

#define NN 100000
#define NE 1600000
#define HID 64
#define NBKT 391            // ceil(NN/256), bucket = dst >> 8
#define TILE 4096
#define EPT 16              // TILE / 256
#define NTILE ((NE + TILE - 1) / TILE)   // 391
#define NSTRIP (NN / 16)    // 6250 (exact)

typedef __attribute__((ext_vector_type(8))) short bf16x8;
typedef __attribute__((ext_vector_type(4))) float f32x4;

__device__ __forceinline__ uint32_t rne_bf16(float v) {
    uint32_t u = __float_as_uint(v);
    return (u + 0x7fffu + ((u >> 16) & 1u)) >> 16;
}

// ---------------- CSR build ----------------

__global__ __launch_bounds__(256) void k_bhist(const int* __restrict__ dst,
                                               int* __restrict__ bcnt) {
    __shared__ int h[NBKT];
    for (int t = threadIdx.x; t < NBKT; t += 256) h[t] = 0;
    __syncthreads();
    int stride = gridDim.x * blockDim.x;
    for (int e = blockIdx.x * blockDim.x + threadIdx.x; e < NE; e += stride)
        atomicAdd(&h[dst[e] >> 8], 1);
    __syncthreads();
    for (int t = threadIdx.x; t < NBKT; t += 256)
        if (h[t]) atomicAdd(&bcnt[t], h[t]);
}

__global__ void k_bscan(const int* __restrict__ bcnt, int* __restrict__ bbase,
                        int* __restrict__ bcur, int* __restrict__ offs) {
    __shared__ int tmp[512];
    int t = threadIdx.x;
    int v = (t < NBKT) ? bcnt[t] : 0;
    int acc = v;
    tmp[t] = v;
    __syncthreads();
    for (int off = 1; off < 512; off <<= 1) {
        int u = (t >= off) ? tmp[t - off] : 0;
        __syncthreads();
        acc += u;
        tmp[t] = acc;
        __syncthreads();
    }
    if (t < NBKT) {
        bbase[t] = acc - v;
        bcur[t]  = acc - v;
    }
    if (t == 0) { bbase[NBKT] = NE; offs[NN] = NE; }
}

__global__ __launch_bounds__(256) void k_bpart(const int* __restrict__ src,
                                               const int* __restrict__ dst,
                                               const float* __restrict__ w,
                                               int* __restrict__ bcur,
                                               int2* __restrict__ bpairs) {
    __shared__ int hcnt[NBKT];
    __shared__ int hbase[NBKT];
    int tile0 = blockIdx.x * TILE;
    for (int t = threadIdx.x; t < NBKT; t += 256) hcnt[t] = 0;
    __syncthreads();

    int   pk[EPT];
    int   bk[EPT];
    float wv[EPT];
    #pragma unroll
    for (int k = 0; k < EPT; k++) {
        int e = tile0 + threadIdx.x + k * 256;
        if (e < NE) {
            int d = dst[e];
            int b = d >> 8;
            pk[k] = (src[e] << 8) | (d & 255);
            wv[k] = w[e];
            bk[k] = b;
            atomicAdd(&hcnt[b], 1);
        } else {
            bk[k] = -1;
        }
    }
    __syncthreads();
    for (int t = threadIdx.x; t < NBKT; t += 256) {
        int c = hcnt[t];
        hbase[t] = c ? atomicAdd(&bcur[t], c) : 0;
        hcnt[t] = 0;
    }
    __syncthreads();
    #pragma unroll
    for (int k = 0; k < EPT; k++) {
        if (bk[k] >= 0) {
            int pos = hbase[bk[k]] + atomicAdd(&hcnt[bk[k]], 1);
            bpairs[pos] = make_int2(pk[k], __float_as_int(wv[k]));
        }
    }
}

__global__ __launch_bounds__(256) void k_bcsr(const int* __restrict__ bbase,
                                              const int2* __restrict__ bpairs,
                                              int* __restrict__ offs,
                                              int2* __restrict__ pairs) {
    __shared__ int cnt[256];
    __shared__ int scn[256];
    __shared__ int cur[256];
    int k = blockIdx.x, t = threadIdx.x;
    int b = bbase[k], e = bbase[k + 1];
    cnt[t] = 0;
    __syncthreads();
    for (int j = b + t; j < e; j += 256)
        atomicAdd(&cnt[bpairs[j].x & 255], 1);
    __syncthreads();
    int v = cnt[t], acc = v;
    scn[t] = v;
    __syncthreads();
    for (int off = 1; off < 256; off <<= 1) {
        int u = (t >= off) ? scn[t - off] : 0;
        __syncthreads();
        acc += u;
        scn[t] = acc;
        __syncthreads();
    }
    int excl = acc - v;
    cur[t] = excl;
    int d = (k << 8) + t;
    if (d < NN) offs[d] = b + excl;
    __syncthreads();
    for (int j = b + t; j < e; j += 256) {
        int2 q = bpairs[j];
        int pos = b + atomicAdd(&cur[q.x & 255], 1);
        pairs[pos] = make_int2(q.x >> 8, q.y);
    }
}

// ---------------- weight hi/lo split ----------------

__global__ __launch_bounds__(256) void k_wsplit(const float* __restrict__ Wrel_mid,
                                                const float* __restrict__ Wroot_mid,
                                                uint16_t* __restrict__ WgH,
                                                uint16_t* __restrict__ WgL,
                                                uint16_t* __restrict__ WrH,
                                                uint16_t* __restrict__ WrL) {
    int i = blockIdx.x * blockDim.x + threadIdx.x;
    if (i >= 3 * 4096) return;
    float a = Wrel_mid[i];
    uint32_t ah = rne_bf16(a);
    float al = a - __uint_as_float(ah << 16);
    WgH[i] = (uint16_t)ah;
    WgL[i] = (uint16_t)rne_bf16(al);
    float b = Wroot_mid[i];
    uint32_t bh = rne_bf16(b);
    float bl = b - __uint_as_float(bh << 16);
    WrH[i] = (uint16_t)bh;
    WrL[i] = (uint16_t)rne_bf16(bl);
}

// ---------------- layers ----------------

__global__ void k_agg_scalar(const int* __restrict__ offs, const int2* __restrict__ pairs,
                             const float* __restrict__ val, float* __restrict__ out) {
    int i = blockIdx.x * blockDim.x + threadIdx.x;
    if (i >= NN) return;
    float a0 = 0.f, a1 = 0.f;
    int b = offs[i], e = offs[i + 1];
    int j = b;
    for (; j + 2 <= e; j += 2) {
        int2 p0 = pairs[j], p1 = pairs[j + 1];
        a0 += __int_as_float(p0.y) * val[p0.x];
        a1 += __int_as_float(p1.y) * val[p1.x];
    }
    for (; j < e; j++) {
        int2 p = pairs[j];
        a0 += __int_as_float(p.y) * val[p.x];
    }
    out[i] = a0 + a1;
}

// h0 = relu(agg0*Wrel0 + brel0 + x*Wroot0), stored single bf16 plane
__global__ void k_layer0(const float* __restrict__ agg0, const float* __restrict__ x,
                         const float* __restrict__ Wrel0, const float* __restrict__ brel0,
                         const float* __restrict__ Wroot0,
                         uint16_t* __restrict__ Hh) {
    int idx = blockIdx.x * blockDim.x + threadIdx.x;  // NN*64 exact
    int i = idx >> 6, c = idx & 63;
    float v = agg0[i] * Wrel0[c] + brel0[c] + x[i] * Wroot0[c];
    v = v > 0.f ? v : 0.f;
    Hh[idx] = (uint16_t)rne_bf16(v);
}

// MFMA pre-transform: H single bf16 plane, W hi/lo (4 MFMAs per tile role).
//   Gb[node][oc] = bf16( Wrel * h )
//   Rb[node][oc] = bf16( Wroot * h + brel )
__global__ __launch_bounds__(256) void k_mfma_pre(
        const uint16_t* __restrict__ Hh,
        const uint16_t* __restrict__ WgH, const uint16_t* __restrict__ WgL,
        const uint16_t* __restrict__ WrH, const uint16_t* __restrict__ WrL,
        const float* __restrict__ brel,
        uint16_t* __restrict__ Gb, uint16_t* __restrict__ Rb) {
    int wave = threadIdx.x >> 6;
    int lane = threadIdx.x & 63;
    int strip = blockIdx.x * 4 + wave;
    if (strip >= NSTRIP) return;
    int row = lane & 15;
    int quad = lane >> 4;
    int anode = strip * 16 + row;
    int kb = quad * 8;

    bf16x8 ah0 = *(const bf16x8*)&Hh[anode * 64 + kb];
    bf16x8 ah1 = *(const bf16x8*)&Hh[anode * 64 + 32 + kb];

    #pragma unroll
    for (int t = 0; t < 4; t++) {
        int oc = t * 16 + row;
        {
            bf16x8 bh0 = *(const bf16x8*)&WgH[oc * 64 + kb];
            bf16x8 bh1 = *(const bf16x8*)&WgH[oc * 64 + 32 + kb];
            bf16x8 bl0 = *(const bf16x8*)&WgL[oc * 64 + kb];
            bf16x8 bl1 = *(const bf16x8*)&WgL[oc * 64 + 32 + kb];
            f32x4 acc = {0.f, 0.f, 0.f, 0.f};
            acc = __builtin_amdgcn_mfma_f32_16x16x32_bf16(ah0, bh0, acc, 0, 0, 0);
            acc = __builtin_amdgcn_mfma_f32_16x16x32_bf16(ah1, bh1, acc, 0, 0, 0);
            acc = __builtin_amdgcn_mfma_f32_16x16x32_bf16(ah0, bl0, acc, 0, 0, 0);
            acc = __builtin_amdgcn_mfma_f32_16x16x32_bf16(ah1, bl1, acc, 0, 0, 0);
            #pragma unroll
            for (int r = 0; r < 4; r++) {
                int nd = strip * 16 + quad * 4 + r;
                Gb[nd * 64 + t * 16 + row] = (uint16_t)rne_bf16(acc[r]);
            }
        }
        {
            bf16x8 bh0 = *(const bf16x8*)&WrH[oc * 64 + kb];
            bf16x8 bh1 = *(const bf16x8*)&WrH[oc * 64 + 32 + kb];
            bf16x8 bl0 = *(const bf16x8*)&WrL[oc * 64 + kb];
            bf16x8 bl1 = *(const bf16x8*)&WrL[oc * 64 + 32 + kb];
            float bias = brel[t * 16 + row];
            f32x4 acc = {bias, bias, bias, bias};
            acc = __builtin_amdgcn_mfma_f32_16x16x32_bf16(ah0, bh0, acc, 0, 0, 0);
            acc = __builtin_amdgcn_mfma_f32_16x16x32_bf16(ah1, bh1, acc, 0, 0, 0);
            acc = __builtin_amdgcn_mfma_f32_16x16x32_bf16(ah0, bl0, acc, 0, 0, 0);
            acc = __builtin_amdgcn_mfma_f32_16x16x32_bf16(ah1, bl1, acc, 0, 0, 0);
            #pragma unroll
            for (int r = 0; r < 4; r++) {
                int nd = strip * 16 + quad * 4 + r;
                Rb[nd * 64 + t * 16 + row] = (uint16_t)rne_bf16(acc[r]);
            }
        }
    }
}

// Aggregation (round-8 structure): 4 adjacent nodes per wave, cooperative
// 64-edge metadata window, segmented per-node scalar-bound loops.
// hout = relu( sum_j w_j*G[src_j] + R[i] ); G,R bf16. LAST: wave-reduce
// s = dot(h,WrelL), r = dot(h,WrootL) instead of storing H.
template <bool LAST>
__global__ __launch_bounds__(256) void k_aggrelu3(
        const int* __restrict__ offs, const int2* __restrict__ pairs,
        const uint16_t* __restrict__ Gb, const uint16_t* __restrict__ Rb,
        uint16_t* __restrict__ Hh,
        const float* __restrict__ WrelL, const float* __restrict__ WrootL,
        float* __restrict__ sarr, float* __restrict__ rarr) {
    int c = threadIdx.x & 63;
    int wid = (blockIdx.x * blockDim.x + threadIdx.x) >> 6;
    int n0 = wid << 2;                // NN % 4 == 0; grid sized exactly
    int ov = (c < 5) ? offs[n0 + c] : 0;
    int bnd[5];
    bnd[0] = __builtin_amdgcn_readlane(ov, 0);
    bnd[1] = __builtin_amdgcn_readlane(ov, 1);
    bnd[2] = __builtin_amdgcn_readlane(ov, 2);
    bnd[3] = __builtin_amdgcn_readlane(ov, 3);
    bnd[4] = __builtin_amdgcn_readlane(ov, 4);

    float accA[4] = {0.f, 0.f, 0.f, 0.f};
    float accB[4] = {0.f, 0.f, 0.f, 0.f};

    for (int cb = bnd[0]; cb < bnd[4]; cb += 64) {
        int n = bnd[4] - cb; if (n > 64) n = 64;
        int2 p = (c < n) ? pairs[cb + c] : make_int2(0, 0);
        #pragma unroll
        for (int t = 0; t < 4; t++) {
            int lo = bnd[t]     > cb     ? bnd[t]     : cb;
            int hi = bnd[t + 1] < cb + n ? bnd[t + 1] : cb + n;
            int j = lo;
            for (; j + 4 <= hi; j += 4) {
                int jj = j - cb;
                int s0 = __builtin_amdgcn_readlane(p.x, jj + 0);
                int s1 = __builtin_amdgcn_readlane(p.x, jj + 1);
                int s2 = __builtin_amdgcn_readlane(p.x, jj + 2);
                int s3 = __builtin_amdgcn_readlane(p.x, jj + 3);
                float w0 = __uint_as_float(__builtin_amdgcn_readlane(p.y, jj + 0));
                float w1 = __uint_as_float(__builtin_amdgcn_readlane(p.y, jj + 1));
                float w2 = __uint_as_float(__builtin_amdgcn_readlane(p.y, jj + 2));
                float w3 = __uint_as_float(__builtin_amdgcn_readlane(p.y, jj + 3));
                uint32_t u0 = Gb[s0 * 64 + c];
                uint32_t u1 = Gb[s1 * 64 + c];
                uint32_t u2 = Gb[s2 * 64 + c];
                uint32_t u3 = Gb[s3 * 64 + c];
                accA[t] += w0 * __uint_as_float(u0 << 16);
                accB[t] += w1 * __uint_as_float(u1 << 16);
                accA[t] += w2 * __uint_as_float(u2 << 16);
                accB[t] += w3 * __uint_as_float(u3 << 16);
            }
            for (; j < hi; j++) {
                int jj = j - cb;
                int s = __builtin_amdgcn_readlane(p.x, jj);
                float wv = __uint_as_float(__builtin_amdgcn_readlane(p.y, jj));
                uint32_t u = Gb[s * 64 + c];
                accA[t] += wv * __uint_as_float(u << 16);
            }
        }
    }
    #pragma unroll
    for (int t = 0; t < 4; t++) {
        uint32_t ur = Rb[(n0 + t) * 64 + c];
        float v = accA[t] + accB[t] + __uint_as_float(ur << 16);
        v = v > 0.f ? v : 0.f;
        if (!LAST) {
            Hh[(n0 + t) * 64 + c] = (uint16_t)rne_bf16(v);
        } else {
            float a = v * WrelL[c];
            float r = v * WrootL[c];
            for (int o = 32; o > 0; o >>= 1) {
                a += __shfl_down(a, o, 64);
                r += __shfl_down(r, o, 64);
            }
            if (c == 0) { sarr[n0 + t] = a; rarr[n0 + t] = r; }
        }
    }
}

__global__ void k_last(const int* __restrict__ offs, const int2* __restrict__ pairs,
                       const float* __restrict__ sarr, const float* __restrict__ rarr,
                       const float* __restrict__ brelL, float* __restrict__ out) {
    int i = blockIdx.x * blockDim.x + threadIdx.x;
    if (i >= NN) return;
    float a0 = rarr[i] + brelL[0], a1 = 0.f;
    int b = offs[i], e = offs[i + 1];
    int j = b;
    for (; j + 2 <= e; j += 2) {
        int2 p0 = pairs[j], p1 = pairs[j + 1];
        a0 += __int_as_float(p0.y) * sarr[p0.x];
        a1 += __int_as_float(p1.y) * sarr[p1.x];
    }
    for (; j < e; j++) {
        int2 p = pairs[j];
        a0 += __int_as_float(p.y) * sarr[p.x];
    }
    out[i] = a0 + a1;
}

extern "C" void kernel_launch(void* const* d_in, const int* in_sizes, int n_in,
                              void* d_out, int out_size, void* d_ws, size_t ws_size,
                              hipStream_t stream) {
    const float* x        = (const float*)d_in[0];
    const int*   ei       = (const int*)d_in[1];
    const float* ew       = (const float*)d_in[2];
    const float* Wrel0    = (const float*)d_in[3];
    const float* brel0    = (const float*)d_in[4];
    const float* Wroot0   = (const float*)d_in[5];
    const float* Wrel_mid = (const float*)d_in[6];
    const float* brel_mid = (const float*)d_in[7];
    const float* Wroot_mid= (const float*)d_in[8];
    const float* WrelL    = (const float*)d_in[9];
    const float* brelL    = (const float*)d_in[10];
    const float* WrootL   = (const float*)d_in[11];
    float* out = (float*)d_out;

    const int* src  = ei;
    const int* dstp = ei + NE;

    char* w = (char*)d_ws;
    size_t o = 0;
    auto alloc = [&](size_t b) -> void* {
        void* r = (void*)(w + o);
        o += (b + 255) & ~(size_t)255;
        return r;
    };
    int*      offs  = (int*)alloc((size_t)(NN + 1) * 4);
    int*      bcnt  = (int*)alloc((size_t)NBKT * 4);
    int*      bbase = (int*)alloc((size_t)(NBKT + 1) * 4);
    int*      bcur  = (int*)alloc((size_t)NBKT * 4);
    uint16_t* WgH   = (uint16_t*)alloc((size_t)3 * 4096 * 2);
    uint16_t* WgL   = (uint16_t*)alloc((size_t)3 * 4096 * 2);
    uint16_t* WrH   = (uint16_t*)alloc((size_t)3 * 4096 * 2);
    uint16_t* WrL   = (uint16_t*)alloc((size_t)3 * 4096 * 2);
    float*    sarr  = (float*)alloc((size_t)NN * 4);
    float*    rarr  = (float*)alloc((size_t)NN * 4);
    int2*     pairs = (int2*)alloc((size_t)NE * 8);
    uint16_t* Hh    = (uint16_t*)alloc((size_t)NN * HID * 2); // 12.8 MB
    uint16_t* Gb    = (uint16_t*)alloc((size_t)NN * HID * 2); // 12.8 MB
    uint16_t* Rb    = (uint16_t*)alloc((size_t)NN * HID * 2); // 12.8 MB
    // bpairs (NE*8B = 12.8MB) aliases pairs-adjacent scratch: use Gb+Rb?
    // bpairs needs 12.8MB and is dead before k_mfma_pre writes Gb; alias Gb.
    int2*  bpairs = (int2*)Gb;
    // agg0 aliases Rb (dead before first k_mfma_pre writes Rb)
    float* agg0 = (float*)Rb;

    hipMemsetAsync(bcnt, 0, (size_t)NBKT * 4, stream);

    // CSR build
    k_bhist<<<512, 256, 0, stream>>>(dstp, bcnt);
    k_bscan<<<1, 512, 0, stream>>>(bcnt, bbase, bcur, offs);
    k_bpart<<<NTILE, 256, 0, stream>>>(src, dstp, ew, bcur, bpairs);
    k_bcsr<<<NBKT, 256, 0, stream>>>(bbase, bpairs, offs, pairs);

    // weight hi/lo split
    k_wsplit<<<(3 * 4096 + 255) / 256, 256, 0, stream>>>(
        Wrel_mid, Wroot_mid, WgH, WgL, WrH, WrL);

    // layer 0 (1-channel input); agg0 aliases Rb, consumed before mfma_pre
    k_agg_scalar<<<(NN + 255) / 256, 256, 0, stream>>>(offs, pairs, x, agg0);
    k_layer0<<<(NN * HID) / 256, 256, 0, stream>>>(agg0, x, Wrel0, brel0, Wroot0, Hh);

    // 3 middle layers; last fuses the final dot-products into its epilogue
    for (int l = 0; l < 3; l++) {
        k_mfma_pre<<<(NSTRIP + 3) / 4, 256, 0, stream>>>(
            Hh,
            WgH + (size_t)l * 4096, WgL + (size_t)l * 4096,
            WrH + (size_t)l * 4096, WrL + (size_t)l * 4096,
            brel_mid + (size_t)l * HID, Gb, Rb);
        if (l < 2) {
            k_aggrelu3<false><<<NN / 16, 256, 0, stream>>>(
                offs, pairs, Gb, Rb, Hh, WrelL, WrootL, sarr, rarr);
        } else {
            k_aggrelu3<true><<<NN / 16, 256, 0, stream>>>(
                offs, pairs, Gb, Rb, Hh, WrelL, WrootL, sarr, rarr);
        }
    }

    // final edge pass on scalars
    k_last<<<(NN + 255) / 256, 256, 0, stream>>>(offs, pairs, sarr, rarr, brelL, out);
}

// Round 11
// 377.436 us; speedup vs baseline: 3.0908x; 1.1068x over previous
//
#include <hip/hip_runtime.h>
#include <stdint.h>

// GraphConv x5 on MI355X — round 11.
// vs round 10:
// (1) Edge records packed to 4 bytes: (bf16_weight[14:0] << 17) | src[16:0]
//     (weights are uniform[0,1) -> sign bit 0; src < 2^17). Aggregation now
//     does ONE v_readlane per edge; src/weight decode is SALU (uniform) and
//     the weight rides as the SGPR operand of v_fmac: 3 VALU/edge (was ~5).
//     Metadata stream halves (12.8 -> 6.4 MB) for all 5 edge passes.
// (2) k_bhist/k_bscan removed: fixed-capacity padded buckets (CAP=8192 vs
//     Poisson mean ~4092) + per-node ends[] array. bcsr gets bucket counts
//     from bpart's final cursors.

#define NN 100000
#define NE 1600000
#define HID 64
#define NBKT 391            // ceil(NN/256), bucket = dst >> 8
#define CAP 8192            // padded bucket capacity (mean 4092, +64 sigma)
#define TILE 4096
#define EPT 16              // TILE / 256
#define NTILE ((NE + TILE - 1) / TILE)   // 391
#define NSTRIP (NN / 16)    // 6250 (exact)

typedef __attribute__((ext_vector_type(8))) short bf16x8;
typedef __attribute__((ext_vector_type(4))) float f32x4;

__device__ __forceinline__ uint32_t rne_bf16(float v) {
    uint32_t u = __float_as_uint(v);
    return (u + 0x7fffu + ((u >> 16) & 1u)) >> 16;
}

// ---------------- CSR build ----------------

__global__ void k_init(int* __restrict__ bcur) {
    int i = blockIdx.x * blockDim.x + threadIdx.x;
    if (i < NBKT) bcur[i] = i * CAP;
}

// tile-local partition into padded buckets: one block per 4096-edge tile
__global__ __launch_bounds__(256) void k_bpart(const int* __restrict__ src,
                                               const int* __restrict__ dst,
                                               const float* __restrict__ w,
                                               int* __restrict__ bcur,
                                               int2* __restrict__ bpairs) {
    __shared__ int hcnt[NBKT];
    __shared__ int hbase[NBKT];
    int tile0 = blockIdx.x * TILE;
    for (int t = threadIdx.x; t < NBKT; t += 256) hcnt[t] = 0;
    __syncthreads();

    int   pk[EPT];
    int   bk[EPT];
    float wv[EPT];
    #pragma unroll
    for (int k = 0; k < EPT; k++) {
        int e = tile0 + threadIdx.x + k * 256;
        if (e < NE) {
            int d = dst[e];
            int b = d >> 8;
            pk[k] = (src[e] << 8) | (d & 255);
            wv[k] = w[e];
            bk[k] = b;
            atomicAdd(&hcnt[b], 1);
        } else {
            bk[k] = -1;
        }
    }
    __syncthreads();
    for (int t = threadIdx.x; t < NBKT; t += 256) {
        int c = hcnt[t];
        hbase[t] = c ? atomicAdd(&bcur[t], c) : 0;
        hcnt[t] = 0;
    }
    __syncthreads();
    #pragma unroll
    for (int k = 0; k < EPT; k++) {
        if (bk[k] >= 0) {
            int pos = hbase[bk[k]] + atomicAdd(&hcnt[bk[k]], 1);
            bpairs[pos] = make_int2(pk[k], __float_as_int(wv[k]));
        }
    }
}

// one block per bucket: LDS counting sort over 256 local dst; emits packed
// 4-byte records + per-node start (offs) and end (ends) arrays.
__global__ __launch_bounds__(256) void k_bcsr(const int* __restrict__ bcur,
                                              const int2* __restrict__ bpairs,
                                              int* __restrict__ offs,
                                              int* __restrict__ ends,
                                              uint32_t* __restrict__ pairs) {
    __shared__ int cnt[256];
    __shared__ int scn[256];
    __shared__ int cur[256];
    int k = blockIdx.x, t = threadIdx.x;
    int base = k * CAP;
    int scnt = bcur[k] - base;          // edges in this bucket
    cnt[t] = 0;
    __syncthreads();
    for (int j = t; j < scnt; j += 256)
        atomicAdd(&cnt[bpairs[base + j].x & 255], 1);
    __syncthreads();
    int v = cnt[t], acc = v;
    scn[t] = v;
    __syncthreads();
    for (int off = 1; off < 256; off <<= 1) {
        int u = (t >= off) ? scn[t - off] : 0;
        __syncthreads();
        acc += u;
        scn[t] = acc;
        __syncthreads();
    }
    int excl = acc - v;
    cur[t] = excl;
    int d = (k << 8) + t;
    if (d < NN) {
        offs[d] = base + excl;
        ends[d] = base + excl + v;
    }
    __syncthreads();
    for (int j = t; j < scnt; j += 256) {
        int2 q = bpairs[base + j];
        int pos = base + atomicAdd(&cur[q.x & 255], 1);
        uint32_t wb = rne_bf16(__int_as_float(q.y)) & 0x7fffu;   // w >= 0
        pairs[pos] = (wb << 17) | (uint32_t)(q.x >> 8);
    }
}

// ---------------- weight hi/lo split ----------------

__global__ __launch_bounds__(256) void k_wsplit(const float* __restrict__ Wrel_mid,
                                                const float* __restrict__ Wroot_mid,
                                                uint16_t* __restrict__ WgH,
                                                uint16_t* __restrict__ WgL,
                                                uint16_t* __restrict__ WrH,
                                                uint16_t* __restrict__ WrL) {
    int i = blockIdx.x * blockDim.x + threadIdx.x;
    if (i >= 3 * 4096) return;
    float a = Wrel_mid[i];
    uint32_t ah = rne_bf16(a);
    float al = a - __uint_as_float(ah << 16);
    WgH[i] = (uint16_t)ah;
    WgL[i] = (uint16_t)rne_bf16(al);
    float b = Wroot_mid[i];
    uint32_t bh = rne_bf16(b);
    float bl = b - __uint_as_float(bh << 16);
    WrH[i] = (uint16_t)bh;
    WrL[i] = (uint16_t)rne_bf16(bl);
}

// ---------------- layers ----------------

__global__ void k_agg_scalar(const int* __restrict__ offs, const int* __restrict__ ends,
                             const uint32_t* __restrict__ pairs,
                             const float* __restrict__ val, float* __restrict__ out) {
    int i = blockIdx.x * blockDim.x + threadIdx.x;
    if (i >= NN) return;
    float a0 = 0.f, a1 = 0.f;
    int b = offs[i], e = ends[i];
    int j = b;
    for (; j + 2 <= e; j += 2) {
        uint32_t r0 = pairs[j], r1 = pairs[j + 1];
        a0 += __uint_as_float((r0 >> 17) << 16) * val[r0 & 0x1ffffu];
        a1 += __uint_as_float((r1 >> 17) << 16) * val[r1 & 0x1ffffu];
    }
    for (; j < e; j++) {
        uint32_t r = pairs[j];
        a0 += __uint_as_float((r >> 17) << 16) * val[r & 0x1ffffu];
    }
    out[i] = a0 + a1;
}

// h0 = relu(agg0*Wrel0 + brel0 + x*Wroot0), stored single bf16 plane
__global__ void k_layer0(const float* __restrict__ agg0, const float* __restrict__ x,
                         const float* __restrict__ Wrel0, const float* __restrict__ brel0,
                         const float* __restrict__ Wroot0,
                         uint16_t* __restrict__ Hh) {
    int idx = blockIdx.x * blockDim.x + threadIdx.x;  // NN*64 exact
    int i = idx >> 6, c = idx & 63;
    float v = agg0[i] * Wrel0[c] + brel0[c] + x[i] * Wroot0[c];
    v = v > 0.f ? v : 0.f;
    Hh[idx] = (uint16_t)rne_bf16(v);
}

// MFMA pre-transform (unchanged from round 10; validated absmax=16).
__global__ __launch_bounds__(256) void k_mfma_pre(
        const uint16_t* __restrict__ Hh,
        const uint16_t* __restrict__ WgH, const uint16_t* __restrict__ WgL,
        const uint16_t* __restrict__ WrH, const uint16_t* __restrict__ WrL,
        const float* __restrict__ brel,
        uint16_t* __restrict__ Gb, uint16_t* __restrict__ Rb) {
    int wave = threadIdx.x >> 6;
    int lane = threadIdx.x & 63;
    int strip = blockIdx.x * 4 + wave;
    if (strip >= NSTRIP) return;
    int row = lane & 15;
    int quad = lane >> 4;
    int anode = strip * 16 + row;
    int kb = quad * 8;

    bf16x8 ah0 = *(const bf16x8*)&Hh[anode * 64 + kb];
    bf16x8 ah1 = *(const bf16x8*)&Hh[anode * 64 + 32 + kb];

    #pragma unroll
    for (int t = 0; t < 4; t++) {
        int oc = t * 16 + row;
        {
            bf16x8 bh0 = *(const bf16x8*)&WgH[oc * 64 + kb];
            bf16x8 bh1 = *(const bf16x8*)&WgH[oc * 64 + 32 + kb];
            bf16x8 bl0 = *(const bf16x8*)&WgL[oc * 64 + kb];
            bf16x8 bl1 = *(const bf16x8*)&WgL[oc * 64 + 32 + kb];
            f32x4 acc = {0.f, 0.f, 0.f, 0.f};
            acc = __builtin_amdgcn_mfma_f32_16x16x32_bf16(ah0, bh0, acc, 0, 0, 0);
            acc = __builtin_amdgcn_mfma_f32_16x16x32_bf16(ah1, bh1, acc, 0, 0, 0);
            acc = __builtin_amdgcn_mfma_f32_16x16x32_bf16(ah0, bl0, acc, 0, 0, 0);
            acc = __builtin_amdgcn_mfma_f32_16x16x32_bf16(ah1, bl1, acc, 0, 0, 0);
            #pragma unroll
            for (int r = 0; r < 4; r++) {
                int nd = strip * 16 + quad * 4 + r;
                Gb[nd * 64 + t * 16 + row] = (uint16_t)rne_bf16(acc[r]);
            }
        }
        {
            bf16x8 bh0 = *(const bf16x8*)&WrH[oc * 64 + kb];
            bf16x8 bh1 = *(const bf16x8*)&WrH[oc * 64 + 32 + kb];
            bf16x8 bl0 = *(const bf16x8*)&WrL[oc * 64 + kb];
            bf16x8 bl1 = *(const bf16x8*)&WrL[oc * 64 + 32 + kb];
            float bias = brel[t * 16 + row];
            f32x4 acc = {bias, bias, bias, bias};
            acc = __builtin_amdgcn_mfma_f32_16x16x32_bf16(ah0, bh0, acc, 0, 0, 0);
            acc = __builtin_amdgcn_mfma_f32_16x16x32_bf16(ah1, bh1, acc, 0, 0, 0);
            acc = __builtin_amdgcn_mfma_f32_16x16x32_bf16(ah0, bl0, acc, 0, 0, 0);
            acc = __builtin_amdgcn_mfma_f32_16x16x32_bf16(ah1, bl1, acc, 0, 0, 0);
            #pragma unroll
            for (int r = 0; r < 4; r++) {
                int nd = strip * 16 + quad * 4 + r;
                Rb[nd * 64 + t * 16 + row] = (uint16_t)rne_bf16(acc[r]);
            }
        }
    }
}

// Aggregation: 4 adjacent nodes/wave, cooperative 64-edge window (one dword
// per lane), segmented per-node loops. Per edge: 1 v_readlane (uniform) ->
// SALU src/weight decode -> 1 gather + 1 shl + 1 v_fmac(SGPR weight).
template <bool LAST>
__global__ __launch_bounds__(256) void k_aggrelu4(
        const int* __restrict__ offs, const int* __restrict__ ends,
        const uint32_t* __restrict__ pairs,
        const uint16_t* __restrict__ Gb, const uint16_t* __restrict__ Rb,
        uint16_t* __restrict__ Hh,
        const float* __restrict__ WrelL, const float* __restrict__ WrootL,
        float* __restrict__ sarr, float* __restrict__ rarr) {
    int c = threadIdx.x & 63;
    int wid = (blockIdx.x * blockDim.x + threadIdx.x) >> 6;
    int n0 = wid << 2;                // NN % 4 == 0; grid sized exactly
    int ov = 0;
    if (c < 4) ov = offs[n0 + c];
    else if (c == 4) ov = ends[n0 + 3];
    int bnd[5];
    bnd[0] = __builtin_amdgcn_readlane(ov, 0);
    bnd[1] = __builtin_amdgcn_readlane(ov, 1);
    bnd[2] = __builtin_amdgcn_readlane(ov, 2);
    bnd[3] = __builtin_amdgcn_readlane(ov, 3);
    bnd[4] = __builtin_amdgcn_readlane(ov, 4);

    float accA[4] = {0.f, 0.f, 0.f, 0.f};
    float accB[4] = {0.f, 0.f, 0.f, 0.f};

    for (int cb = bnd[0]; cb < bnd[4]; cb += 64) {
        int n = bnd[4] - cb; if (n > 64) n = 64;
        uint32_t p = (c < n) ? pairs[cb + c] : 0u;
        #pragma unroll
        for (int t = 0; t < 4; t++) {
            int lo = bnd[t]     > cb     ? bnd[t]     : cb;
            int hi = bnd[t + 1] < cb + n ? bnd[t + 1] : cb + n;
            int j = lo;
            for (; j + 8 <= hi; j += 8) {
                int jj = j - cb;
                uint32_t r0 = __builtin_amdgcn_readlane(p, jj + 0);
                uint32_t r1 = __builtin_amdgcn_readlane(p, jj + 1);
                uint32_t r2 = __builtin_amdgcn_readlane(p, jj + 2);
                uint32_t r3 = __builtin_amdgcn_readlane(p, jj + 3);
                uint32_t r4 = __builtin_amdgcn_readlane(p, jj + 4);
                uint32_t r5 = __builtin_amdgcn_readlane(p, jj + 5);
                uint32_t r6 = __builtin_amdgcn_readlane(p, jj + 6);
                uint32_t r7 = __builtin_amdgcn_readlane(p, jj + 7);
                uint32_t u0 = Gb[(r0 & 0x1ffffu) * 64 + c];
                uint32_t u1 = Gb[(r1 & 0x1ffffu) * 64 + c];
                uint32_t u2 = Gb[(r2 & 0x1ffffu) * 64 + c];
                uint32_t u3 = Gb[(r3 & 0x1ffffu) * 64 + c];
                uint32_t u4 = Gb[(r4 & 0x1ffffu) * 64 + c];
                uint32_t u5 = Gb[(r5 & 0x1ffffu) * 64 + c];
                uint32_t u6 = Gb[(r6 & 0x1ffffu) * 64 + c];
                uint32_t u7 = Gb[(r7 & 0x1ffffu) * 64 + c];
                accA[t] += __uint_as_float((r0 >> 17) << 16) * __uint_as_float(u0 << 16);
                accB[t] += __uint_as_float((r1 >> 17) << 16) * __uint_as_float(u1 << 16);
                accA[t] += __uint_as_float((r2 >> 17) << 16) * __uint_as_float(u2 << 16);
                accB[t] += __uint_as_float((r3 >> 17) << 16) * __uint_as_float(u3 << 16);
                accA[t] += __uint_as_float((r4 >> 17) << 16) * __uint_as_float(u4 << 16);
                accB[t] += __uint_as_float((r5 >> 17) << 16) * __uint_as_float(u5 << 16);
                accA[t] += __uint_as_float((r6 >> 17) << 16) * __uint_as_float(u6 << 16);
                accB[t] += __uint_as_float((r7 >> 17) << 16) * __uint_as_float(u7 << 16);
            }
            for (; j + 4 <= hi; j += 4) {
                int jj = j - cb;
                uint32_t r0 = __builtin_amdgcn_readlane(p, jj + 0);
                uint32_t r1 = __builtin_amdgcn_readlane(p, jj + 1);
                uint32_t r2 = __builtin_amdgcn_readlane(p, jj + 2);
                uint32_t r3 = __builtin_amdgcn_readlane(p, jj + 3);
                uint32_t u0 = Gb[(r0 & 0x1ffffu) * 64 + c];
                uint32_t u1 = Gb[(r1 & 0x1ffffu) * 64 + c];
                uint32_t u2 = Gb[(r2 & 0x1ffffu) * 64 + c];
                uint32_t u3 = Gb[(r3 & 0x1ffffu) * 64 + c];
                accA[t] += __uint_as_float((r0 >> 17) << 16) * __uint_as_float(u0 << 16);
                accB[t] += __uint_as_float((r1 >> 17) << 16) * __uint_as_float(u1 << 16);
                accA[t] += __uint_as_float((r2 >> 17) << 16) * __uint_as_float(u2 << 16);
                accB[t] += __uint_as_float((r3 >> 17) << 16) * __uint_as_float(u3 << 16);
            }
            for (; j < hi; j++) {
                int jj = j - cb;
                uint32_t r = __builtin_amdgcn_readlane(p, jj);
                uint32_t u = Gb[(r & 0x1ffffu) * 64 + c];
                accA[t] += __uint_as_float((r >> 17) << 16) * __uint_as_float(u << 16);
            }
        }
    }
    #pragma unroll
    for (int t = 0; t < 4; t++) {
        uint32_t ur = Rb[(n0 + t) * 64 + c];
        float v = accA[t] + accB[t] + __uint_as_float(ur << 16);
        v = v > 0.f ? v : 0.f;
        if (!LAST) {
            Hh[(n0 + t) * 64 + c] = (uint16_t)rne_bf16(v);
        } else {
            float a = v * WrelL[c];
            float r = v * WrootL[c];
            for (int o = 32; o > 0; o >>= 1) {
                a += __shfl_down(a, o, 64);
                r += __shfl_down(r, o, 64);
            }
            if (c == 0) { sarr[n0 + t] = a; rarr[n0 + t] = r; }
        }
    }
}

__global__ void k_last(const int* __restrict__ offs, const int* __restrict__ ends,
                       const uint32_t* __restrict__ pairs,
                       const float* __restrict__ sarr, const float* __restrict__ rarr,
                       const float* __restrict__ brelL, float* __restrict__ out) {
    int i = blockIdx.x * blockDim.x + threadIdx.x;
    if (i >= NN) return;
    float a0 = rarr[i] + brelL[0], a1 = 0.f;
    int b = offs[i], e = ends[i];
    int j = b;
    for (; j + 2 <= e; j += 2) {
        uint32_t r0 = pairs[j], r1 = pairs[j + 1];
        a0 += __uint_as_float((r0 >> 17) << 16) * sarr[r0 & 0x1ffffu];
        a1 += __uint_as_float((r1 >> 17) << 16) * sarr[r1 & 0x1ffffu];
    }
    for (; j < e; j++) {
        uint32_t r = pairs[j];
        a0 += __uint_as_float((r >> 17) << 16) * sarr[r & 0x1ffffu];
    }
    out[i] = a0 + a1;
}

extern "C" void kernel_launch(void* const* d_in, const int* in_sizes, int n_in,
                              void* d_out, int out_size, void* d_ws, size_t ws_size,
                              hipStream_t stream) {
    const float* x        = (const float*)d_in[0];
    const int*   ei       = (const int*)d_in[1];
    const float* ew       = (const float*)d_in[2];
    const float* Wrel0    = (const float*)d_in[3];
    const float* brel0    = (const float*)d_in[4];
    const float* Wroot0   = (const float*)d_in[5];
    const float* Wrel_mid = (const float*)d_in[6];
    const float* brel_mid = (const float*)d_in[7];
    const float* Wroot_mid= (const float*)d_in[8];
    const float* WrelL    = (const float*)d_in[9];
    const float* brelL    = (const float*)d_in[10];
    const float* WrootL   = (const float*)d_in[11];
    float* out = (float*)d_out;

    const int* src  = ei;
    const int* dstp = ei + NE;

    char* w = (char*)d_ws;
    size_t o = 0;
    auto alloc = [&](size_t b) -> void* {
        void* r = (void*)(w + o);
        o += (b + 255) & ~(size_t)255;
        return r;
    };
    int*      offs  = (int*)alloc((size_t)NN * 4);
    int*      ends  = (int*)alloc((size_t)NN * 4);
    int*      bcur  = (int*)alloc((size_t)NBKT * 4);
    uint16_t* WgH   = (uint16_t*)alloc((size_t)3 * 4096 * 2);
    uint16_t* WgL   = (uint16_t*)alloc((size_t)3 * 4096 * 2);
    uint16_t* WrH   = (uint16_t*)alloc((size_t)3 * 4096 * 2);
    uint16_t* WrL   = (uint16_t*)alloc((size_t)3 * 4096 * 2);
    float*    sarr  = (float*)alloc((size_t)NN * 4);
    float*    rarr  = (float*)alloc((size_t)NN * 4);
    uint32_t* pairs = (uint32_t*)alloc((size_t)NBKT * CAP * 4);  // 12.8 MB padded
    uint16_t* Hh    = (uint16_t*)alloc((size_t)NN * HID * 2);    // 12.8 MB
    uint16_t* Gb    = (uint16_t*)alloc((size_t)NN * HID * 2);    // 12.8 MB (exactly 50000*256B)
    uint16_t* Rb    = (uint16_t*)alloc((size_t)NN * HID * 2);    // 12.8 MB
    // bpairs (NBKT*CAP*8B = 25.6MB) aliases Gb+Rb (contiguous, dead before
    // the first k_mfma_pre writes them)
    int2*  bpairs = (int2*)Gb;
    // agg0 aliases Hh? no — layer0 writes Hh from agg0. agg0 aliases sarr
    // (sarr only written by the LAST aggrelu, long after agg0 is consumed).
    float* agg0 = sarr;

    // CSR build (padded buckets; no global histogram/scan passes)
    k_init<<<(NBKT + 255) / 256, 256, 0, stream>>>(bcur);
    k_bpart<<<NTILE, 256, 0, stream>>>(src, dstp, ew, bcur, bpairs);
    k_bcsr<<<NBKT, 256, 0, stream>>>(bcur, bpairs, offs, ends, pairs);

    // weight hi/lo split
    k_wsplit<<<(3 * 4096 + 255) / 256, 256, 0, stream>>>(
        Wrel_mid, Wroot_mid, WgH, WgL, WrH, WrL);

    // layer 0 (1-channel input)
    k_agg_scalar<<<(NN + 255) / 256, 256, 0, stream>>>(offs, ends, pairs, x, agg0);
    k_layer0<<<(NN * HID) / 256, 256, 0, stream>>>(agg0, x, Wrel0, brel0, Wroot0, Hh);

    // 3 middle layers; last fuses the final dot-products into its epilogue
    for (int l = 0; l < 3; l++) {
        k_mfma_pre<<<(NSTRIP + 3) / 4, 256, 0, stream>>>(
            Hh,
            WgH + (size_t)l * 4096, WgL + (size_t)l * 4096,
            WrH + (size_t)l * 4096, WrL + (size_t)l * 4096,
            brel_mid + (size_t)l * HID, Gb, Rb);
        if (l < 2) {
            k_aggrelu4<false><<<NN / 16, 256, 0, stream>>>(
                offs, ends, pairs, Gb, Rb, Hh, WrelL, WrootL, sarr, rarr);
        } else {
            k_aggrelu4<true><<<NN / 16, 256, 0, stream>>>(
                offs, ends, pairs, Gb, Rb, Hh, WrelL, WrootL, sarr, rarr);
        }
    }

    // final edge pass on scalars
    k_last<<<(NN + 255) / 256, 256, 0, stream>>>(offs, ends, pairs, sarr, rarr, brelL, out);
}

// Round 12
// 350.660 us; speedup vs baseline: 3.3268x; 1.0764x over previous
//
#include <hip/hip_runtime.h>
#include <stdint.h>

// GraphConv x5 on MI355X — round 12.
// vs round 11: mfma_pre fused into the aggregation epilogue. Block = 16 nodes
// (4 waves x 4 nodes; aggregation inner loop identical to round 11). Epilogue:
// h staged as packed bf16 in LDS (stride 36 dwords, <=2-way banks), then each
// wave computes one 16-oc G-tile + one 16-oc R-tile with the validated MFMA
// fragment code (4 MFMAs each, W hi/lo). Deletes the Hh buffer (25.6MB/layer
// round-trip), 3 mfma_pre launches, and the layer0 store-reload (layer0 gets
// the same epilogue). G/R ping-pong between two buffer sets.

#define NN 100000
#define NE 1600000
#define HID 64
#define NBKT 391            // ceil(NN/256), bucket = dst >> 8
#define CAP 8192            // padded bucket capacity (mean 4092, +64 sigma)
#define TILE 4096
#define EPT 16              // TILE / 256
#define NTILE ((NE + TILE - 1) / TILE)   // 391

typedef __attribute__((ext_vector_type(8))) short bf16x8;
typedef __attribute__((ext_vector_type(4))) float f32x4;

__device__ __forceinline__ uint32_t rne_bf16(float v) {
    uint32_t u = __float_as_uint(v);
    return (u + 0x7fffu + ((u >> 16) & 1u)) >> 16;
}

// ---------------- CSR build ----------------

__global__ void k_init(int* __restrict__ bcur) {
    int i = blockIdx.x * blockDim.x + threadIdx.x;
    if (i < NBKT) bcur[i] = i * CAP;
}

__global__ __launch_bounds__(256) void k_bpart(const int* __restrict__ src,
                                               const int* __restrict__ dst,
                                               const float* __restrict__ w,
                                               int* __restrict__ bcur,
                                               int2* __restrict__ bpairs) {
    __shared__ int hcnt[NBKT];
    __shared__ int hbase[NBKT];
    int tile0 = blockIdx.x * TILE;
    for (int t = threadIdx.x; t < NBKT; t += 256) hcnt[t] = 0;
    __syncthreads();

    int   pk[EPT];
    int   bk[EPT];
    float wv[EPT];
    #pragma unroll
    for (int k = 0; k < EPT; k++) {
        int e = tile0 + threadIdx.x + k * 256;
        if (e < NE) {
            int d = dst[e];
            int b = d >> 8;
            pk[k] = (src[e] << 8) | (d & 255);
            wv[k] = w[e];
            bk[k] = b;
            atomicAdd(&hcnt[b], 1);
        } else {
            bk[k] = -1;
        }
    }
    __syncthreads();
    for (int t = threadIdx.x; t < NBKT; t += 256) {
        int c = hcnt[t];
        hbase[t] = c ? atomicAdd(&bcur[t], c) : 0;
        hcnt[t] = 0;
    }
    __syncthreads();
    #pragma unroll
    for (int k = 0; k < EPT; k++) {
        if (bk[k] >= 0) {
            int pos = hbase[bk[k]] + atomicAdd(&hcnt[bk[k]], 1);
            bpairs[pos] = make_int2(pk[k], __float_as_int(wv[k]));
        }
    }
}

__global__ __launch_bounds__(256) void k_bcsr(const int* __restrict__ bcur,
                                              const int2* __restrict__ bpairs,
                                              int* __restrict__ offs,
                                              int* __restrict__ ends,
                                              uint32_t* __restrict__ pairs) {
    __shared__ int cnt[256];
    __shared__ int scn[256];
    __shared__ int cur[256];
    int k = blockIdx.x, t = threadIdx.x;
    int base = k * CAP;
    int scnt = bcur[k] - base;
    cnt[t] = 0;
    __syncthreads();
    for (int j = t; j < scnt; j += 256)
        atomicAdd(&cnt[bpairs[base + j].x & 255], 1);
    __syncthreads();
    int v = cnt[t], acc = v;
    scn[t] = v;
    __syncthreads();
    for (int off = 1; off < 256; off <<= 1) {
        int u = (t >= off) ? scn[t - off] : 0;
        __syncthreads();
        acc += u;
        scn[t] = acc;
        __syncthreads();
    }
    int excl = acc - v;
    cur[t] = excl;
    int d = (k << 8) + t;
    if (d < NN) {
        offs[d] = base + excl;
        ends[d] = base + excl + v;
    }
    __syncthreads();
    for (int j = t; j < scnt; j += 256) {
        int2 q = bpairs[base + j];
        int pos = base + atomicAdd(&cur[q.x & 255], 1);
        uint32_t wb = rne_bf16(__int_as_float(q.y)) & 0x7fffu;   // w >= 0
        pairs[pos] = (wb << 17) | (uint32_t)(q.x >> 8);
    }
}

// ---------------- weight hi/lo split ----------------

__global__ __launch_bounds__(256) void k_wsplit(const float* __restrict__ Wrel_mid,
                                                const float* __restrict__ Wroot_mid,
                                                uint16_t* __restrict__ WgH,
                                                uint16_t* __restrict__ WgL,
                                                uint16_t* __restrict__ WrH,
                                                uint16_t* __restrict__ WrL) {
    int i = blockIdx.x * blockDim.x + threadIdx.x;
    if (i >= 3 * 4096) return;
    float a = Wrel_mid[i];
    uint32_t ah = rne_bf16(a);
    float al = a - __uint_as_float(ah << 16);
    WgH[i] = (uint16_t)ah;
    WgL[i] = (uint16_t)rne_bf16(al);
    float b = Wroot_mid[i];
    uint32_t bh = rne_bf16(b);
    float bl = b - __uint_as_float(bh << 16);
    WrH[i] = (uint16_t)bh;
    WrL[i] = (uint16_t)rne_bf16(bl);
}

// ---------------- shared epilogue: 16-node h (LDS) -> G,R tiles ----------------
// sH: 16 rows x 36 dwords (packed bf16 channel pairs). Wave w computes the
// oc-tile [w*16, w*16+16) for both G and R using the validated fragment maps:
// A[m=lane&15][k=quad*8+j], B[n=lane&15][k=quad*8+j], D col=lane&15,
// row=quad*4+reg.
__device__ __forceinline__ void mfma_epilogue(
        int lane, int w, int blk16, const uint32_t* sH,
        const uint16_t* __restrict__ WgH, const uint16_t* __restrict__ WgL,
        const uint16_t* __restrict__ WrH, const uint16_t* __restrict__ WrL,
        const float* __restrict__ brel,
        uint16_t* __restrict__ Gout, uint16_t* __restrict__ Rout) {
    int row = lane & 15;
    int quad = lane >> 4;
    int kb = quad * 8;
    bf16x8 ah0 = *(const bf16x8*)&sH[row * 36 + quad * 4];
    bf16x8 ah1 = *(const bf16x8*)&sH[row * 36 + 16 + quad * 4];
    int oc = w * 16 + row;
    {
        bf16x8 bh0 = *(const bf16x8*)&WgH[oc * 64 + kb];
        bf16x8 bh1 = *(const bf16x8*)&WgH[oc * 64 + 32 + kb];
        bf16x8 bl0 = *(const bf16x8*)&WgL[oc * 64 + kb];
        bf16x8 bl1 = *(const bf16x8*)&WgL[oc * 64 + 32 + kb];
        f32x4 acc = {0.f, 0.f, 0.f, 0.f};
        acc = __builtin_amdgcn_mfma_f32_16x16x32_bf16(ah0, bh0, acc, 0, 0, 0);
        acc = __builtin_amdgcn_mfma_f32_16x16x32_bf16(ah1, bh1, acc, 0, 0, 0);
        acc = __builtin_amdgcn_mfma_f32_16x16x32_bf16(ah0, bl0, acc, 0, 0, 0);
        acc = __builtin_amdgcn_mfma_f32_16x16x32_bf16(ah1, bl1, acc, 0, 0, 0);
        #pragma unroll
        for (int r = 0; r < 4; r++) {
            int nd = blk16 + quad * 4 + r;
            Gout[nd * 64 + oc] = (uint16_t)rne_bf16(acc[r]);
        }
    }
    {
        bf16x8 bh0 = *(const bf16x8*)&WrH[oc * 64 + kb];
        bf16x8 bh1 = *(const bf16x8*)&WrH[oc * 64 + 32 + kb];
        bf16x8 bl0 = *(const bf16x8*)&WrL[oc * 64 + kb];
        bf16x8 bl1 = *(const bf16x8*)&WrL[oc * 64 + 32 + kb];
        float bias = brel[oc];
        f32x4 acc = {bias, bias, bias, bias};
        acc = __builtin_amdgcn_mfma_f32_16x16x32_bf16(ah0, bh0, acc, 0, 0, 0);
        acc = __builtin_amdgcn_mfma_f32_16x16x32_bf16(ah1, bh1, acc, 0, 0, 0);
        acc = __builtin_amdgcn_mfma_f32_16x16x32_bf16(ah0, bl0, acc, 0, 0, 0);
        acc = __builtin_amdgcn_mfma_f32_16x16x32_bf16(ah1, bl1, acc, 0, 0, 0);
        #pragma unroll
        for (int r = 0; r < 4; r++) {
            int nd = blk16 + quad * 4 + r;
            Rout[nd * 64 + oc] = (uint16_t)rne_bf16(acc[r]);
        }
    }
}

// ---------------- layers ----------------

__global__ void k_agg_scalar(const int* __restrict__ offs, const int* __restrict__ ends,
                             const uint32_t* __restrict__ pairs,
                             const float* __restrict__ val, float* __restrict__ out) {
    int i = blockIdx.x * blockDim.x + threadIdx.x;
    if (i >= NN) return;
    float a0 = 0.f, a1 = 0.f;
    int b = offs[i], e = ends[i];
    int j = b;
    for (; j + 2 <= e; j += 2) {
        uint32_t r0 = pairs[j], r1 = pairs[j + 1];
        a0 += __uint_as_float((r0 >> 17) << 16) * val[r0 & 0x1ffffu];
        a1 += __uint_as_float((r1 >> 17) << 16) * val[r1 & 0x1ffffu];
    }
    for (; j < e; j++) {
        uint32_t r = pairs[j];
        a0 += __uint_as_float((r >> 17) << 16) * val[r & 0x1ffffu];
    }
    out[i] = a0 + a1;
}

// layer0 + pre-transform for mid-layer 0: h0 = relu(agg0*Wrel0+b0+x*Wroot0)
// staged in LDS, then MFMA epilogue -> G1, R1.
__global__ __launch_bounds__(256) void k_l0pre(
        const float* __restrict__ agg0, const float* __restrict__ x,
        const float* __restrict__ Wrel0, const float* __restrict__ brel0,
        const float* __restrict__ Wroot0,
        const uint16_t* __restrict__ WgH, const uint16_t* __restrict__ WgL,
        const uint16_t* __restrict__ WrH, const uint16_t* __restrict__ WrL,
        const float* __restrict__ brel,
        uint16_t* __restrict__ Gout, uint16_t* __restrict__ Rout) {
    __shared__ uint32_t sH[16 * 36];
    int c = threadIdx.x & 63;
    int w = threadIdx.x >> 6;
    int blk16 = blockIdx.x * 16;
    float wr = Wrel0[c], br = brel0[c], wo = Wroot0[c];
    #pragma unroll
    for (int t = 0; t < 4; t++) {
        int node = blk16 + w * 4 + t;
        float v = agg0[node] * wr + br + x[node] * wo;
        v = v > 0.f ? v : 0.f;
        uint32_t hb = rne_bf16(v);
        uint32_t pn = (uint32_t)__shfl_xor((int)hb, 1, 64);
        if (!(c & 1)) sH[(w * 4 + t) * 36 + (c >> 1)] = hb | (pn << 16);
    }
    __syncthreads();
    mfma_epilogue(c, w, blk16, sH, WgH, WgL, WrH, WrL, brel, Gout, Rout);
}

// Fused aggregation + pre-transform. Aggregation inner loop identical to
// round 11 (4 adjacent nodes/wave, cooperative 64-edge window, 1 readlane
// per edge). !LAST: epilogue produces next layer's G,R from LDS-staged h.
// LAST: wave-reduces s = dot(h,WrelL), r = dot(h,WrootL).
template <bool LAST>
__global__ __launch_bounds__(256) void k_aggfused(
        const int* __restrict__ offs, const int* __restrict__ ends,
        const uint32_t* __restrict__ pairs,
        const uint16_t* __restrict__ Gb, const uint16_t* __restrict__ Rb,
        const uint16_t* __restrict__ WgH, const uint16_t* __restrict__ WgL,
        const uint16_t* __restrict__ WrH, const uint16_t* __restrict__ WrL,
        const float* __restrict__ brel,
        uint16_t* __restrict__ Gout, uint16_t* __restrict__ Rout,
        const float* __restrict__ WrelL, const float* __restrict__ WrootL,
        float* __restrict__ sarr, float* __restrict__ rarr) {
    __shared__ uint32_t sH[16 * 36];
    int c = threadIdx.x & 63;
    int w = threadIdx.x >> 6;
    int blk16 = blockIdx.x * 16;
    int n0 = blk16 + w * 4;
    int ov = 0;
    if (c < 4) ov = offs[n0 + c];
    else if (c == 4) ov = ends[n0 + 3];
    int bnd[5];
    bnd[0] = __builtin_amdgcn_readlane(ov, 0);
    bnd[1] = __builtin_amdgcn_readlane(ov, 1);
    bnd[2] = __builtin_amdgcn_readlane(ov, 2);
    bnd[3] = __builtin_amdgcn_readlane(ov, 3);
    bnd[4] = __builtin_amdgcn_readlane(ov, 4);

    float accA[4] = {0.f, 0.f, 0.f, 0.f};
    float accB[4] = {0.f, 0.f, 0.f, 0.f};

    for (int cb = bnd[0]; cb < bnd[4]; cb += 64) {
        int n = bnd[4] - cb; if (n > 64) n = 64;
        uint32_t p = (c < n) ? pairs[cb + c] : 0u;
        #pragma unroll
        for (int t = 0; t < 4; t++) {
            int lo = bnd[t]     > cb     ? bnd[t]     : cb;
            int hi = bnd[t + 1] < cb + n ? bnd[t + 1] : cb + n;
            int j = lo;
            for (; j + 8 <= hi; j += 8) {
                int jj = j - cb;
                uint32_t r0 = __builtin_amdgcn_readlane(p, jj + 0);
                uint32_t r1 = __builtin_amdgcn_readlane(p, jj + 1);
                uint32_t r2 = __builtin_amdgcn_readlane(p, jj + 2);
                uint32_t r3 = __builtin_amdgcn_readlane(p, jj + 3);
                uint32_t r4 = __builtin_amdgcn_readlane(p, jj + 4);
                uint32_t r5 = __builtin_amdgcn_readlane(p, jj + 5);
                uint32_t r6 = __builtin_amdgcn_readlane(p, jj + 6);
                uint32_t r7 = __builtin_amdgcn_readlane(p, jj + 7);
                uint32_t u0 = Gb[(r0 & 0x1ffffu) * 64 + c];
                uint32_t u1 = Gb[(r1 & 0x1ffffu) * 64 + c];
                uint32_t u2 = Gb[(r2 & 0x1ffffu) * 64 + c];
                uint32_t u3 = Gb[(r3 & 0x1ffffu) * 64 + c];
                uint32_t u4 = Gb[(r4 & 0x1ffffu) * 64 + c];
                uint32_t u5 = Gb[(r5 & 0x1ffffu) * 64 + c];
                uint32_t u6 = Gb[(r6 & 0x1ffffu) * 64 + c];
                uint32_t u7 = Gb[(r7 & 0x1ffffu) * 64 + c];
                accA[t] += __uint_as_float((r0 >> 17) << 16) * __uint_as_float(u0 << 16);
                accB[t] += __uint_as_float((r1 >> 17) << 16) * __uint_as_float(u1 << 16);
                accA[t] += __uint_as_float((r2 >> 17) << 16) * __uint_as_float(u2 << 16);
                accB[t] += __uint_as_float((r3 >> 17) << 16) * __uint_as_float(u3 << 16);
                accA[t] += __uint_as_float((r4 >> 17) << 16) * __uint_as_float(u4 << 16);
                accB[t] += __uint_as_float((r5 >> 17) << 16) * __uint_as_float(u5 << 16);
                accA[t] += __uint_as_float((r6 >> 17) << 16) * __uint_as_float(u6 << 16);
                accB[t] += __uint_as_float((r7 >> 17) << 16) * __uint_as_float(u7 << 16);
            }
            for (; j + 4 <= hi; j += 4) {
                int jj = j - cb;
                uint32_t r0 = __builtin_amdgcn_readlane(p, jj + 0);
                uint32_t r1 = __builtin_amdgcn_readlane(p, jj + 1);
                uint32_t r2 = __builtin_amdgcn_readlane(p, jj + 2);
                uint32_t r3 = __builtin_amdgcn_readlane(p, jj + 3);
                uint32_t u0 = Gb[(r0 & 0x1ffffu) * 64 + c];
                uint32_t u1 = Gb[(r1 & 0x1ffffu) * 64 + c];
                uint32_t u2 = Gb[(r2 & 0x1ffffu) * 64 + c];
                uint32_t u3 = Gb[(r3 & 0x1ffffu) * 64 + c];
                accA[t] += __uint_as_float((r0 >> 17) << 16) * __uint_as_float(u0 << 16);
                accB[t] += __uint_as_float((r1 >> 17) << 16) * __uint_as_float(u1 << 16);
                accA[t] += __uint_as_float((r2 >> 17) << 16) * __uint_as_float(u2 << 16);
                accB[t] += __uint_as_float((r3 >> 17) << 16) * __uint_as_float(u3 << 16);
            }
            for (; j < hi; j++) {
                int jj = j - cb;
                uint32_t r = __builtin_amdgcn_readlane(p, jj);
                uint32_t u = Gb[(r & 0x1ffffu) * 64 + c];
                accA[t] += __uint_as_float((r >> 17) << 16) * __uint_as_float(u << 16);
            }
        }
    }
    #pragma unroll
    for (int t = 0; t < 4; t++) {
        uint32_t ur = Rb[(n0 + t) * 64 + c];
        float v = accA[t] + accB[t] + __uint_as_float(ur << 16);
        v = v > 0.f ? v : 0.f;
        if (!LAST) {
            uint32_t hb = rne_bf16(v);
            uint32_t pn = (uint32_t)__shfl_xor((int)hb, 1, 64);
            if (!(c & 1)) sH[(w * 4 + t) * 36 + (c >> 1)] = hb | (pn << 16);
        } else {
            float a = v * WrelL[c];
            float r = v * WrootL[c];
            for (int o = 32; o > 0; o >>= 1) {
                a += __shfl_down(a, o, 64);
                r += __shfl_down(r, o, 64);
            }
            if (c == 0) { sarr[n0 + t] = a; rarr[n0 + t] = r; }
        }
    }
    if (!LAST) {
        __syncthreads();
        mfma_epilogue(c, w, blk16, sH, WgH, WgL, WrH, WrL, brel, Gout, Rout);
    }
}

__global__ void k_last(const int* __restrict__ offs, const int* __restrict__ ends,
                       const uint32_t* __restrict__ pairs,
                       const float* __restrict__ sarr, const float* __restrict__ rarr,
                       const float* __restrict__ brelL, float* __restrict__ out) {
    int i = blockIdx.x * blockDim.x + threadIdx.x;
    if (i >= NN) return;
    float a0 = rarr[i] + brelL[0], a1 = 0.f;
    int b = offs[i], e = ends[i];
    int j = b;
    for (; j + 2 <= e; j += 2) {
        uint32_t r0 = pairs[j], r1 = pairs[j + 1];
        a0 += __uint_as_float((r0 >> 17) << 16) * sarr[r0 & 0x1ffffu];
        a1 += __uint_as_float((r1 >> 17) << 16) * sarr[r1 & 0x1ffffu];
    }
    for (; j < e; j++) {
        uint32_t r = pairs[j];
        a0 += __uint_as_float((r >> 17) << 16) * sarr[r & 0x1ffffu];
    }
    out[i] = a0 + a1;
}

extern "C" void kernel_launch(void* const* d_in, const int* in_sizes, int n_in,
                              void* d_out, int out_size, void* d_ws, size_t ws_size,
                              hipStream_t stream) {
    const float* x        = (const float*)d_in[0];
    const int*   ei       = (const int*)d_in[1];
    const float* ew       = (const float*)d_in[2];
    const float* Wrel0    = (const float*)d_in[3];
    const float* brel0    = (const float*)d_in[4];
    const float* Wroot0   = (const float*)d_in[5];
    const float* Wrel_mid = (const float*)d_in[6];
    const float* brel_mid = (const float*)d_in[7];
    const float* Wroot_mid= (const float*)d_in[8];
    const float* WrelL    = (const float*)d_in[9];
    const float* brelL    = (const float*)d_in[10];
    const float* WrootL   = (const float*)d_in[11];
    float* out = (float*)d_out;

    const int* src  = ei;
    const int* dstp = ei + NE;

    char* w = (char*)d_ws;
    size_t o = 0;
    auto alloc = [&](size_t b) -> void* {
        void* r = (void*)(w + o);
        o += (b + 255) & ~(size_t)255;
        return r;
    };
    int*      offs  = (int*)alloc((size_t)NN * 4);
    int*      ends  = (int*)alloc((size_t)NN * 4);
    int*      bcur  = (int*)alloc((size_t)NBKT * 4);
    uint16_t* WgH   = (uint16_t*)alloc((size_t)3 * 4096 * 2);
    uint16_t* WgL   = (uint16_t*)alloc((size_t)3 * 4096 * 2);
    uint16_t* WrH   = (uint16_t*)alloc((size_t)3 * 4096 * 2);
    uint16_t* WrL   = (uint16_t*)alloc((size_t)3 * 4096 * 2);
    float*    sarr  = (float*)alloc((size_t)NN * 4);
    float*    rarr  = (float*)alloc((size_t)NN * 4);
    uint32_t* pairs = (uint32_t*)alloc((size_t)NBKT * CAP * 4);  // 12.8 MB padded
    uint16_t* GbA   = (uint16_t*)alloc((size_t)NN * HID * 2);    // 12.8 MB
    uint16_t* RbA   = (uint16_t*)alloc((size_t)NN * HID * 2);
    uint16_t* GbB   = (uint16_t*)alloc((size_t)NN * HID * 2);    // GbB/RbB contiguous
    uint16_t* RbB   = (uint16_t*)alloc((size_t)NN * HID * 2);
    (void)RbB;
    // bpairs (NBKT*CAP*8B = 25.6MB) aliases GbB+RbB (contiguous; dead before
    // the first k_aggfused writes set B)
    int2*  bpairs = (int2*)GbB;
    // agg0 aliases sarr (sarr written only by the LAST fused kernel, long
    // after agg0 is consumed by k_l0pre)
    float* agg0 = sarr;

    // CSR build (padded buckets)
    k_init<<<(NBKT + 255) / 256, 256, 0, stream>>>(bcur);
    k_bpart<<<NTILE, 256, 0, stream>>>(src, dstp, ew, bcur, bpairs);
    k_bcsr<<<NBKT, 256, 0, stream>>>(bcur, bpairs, offs, ends, pairs);

    // weight hi/lo split
    k_wsplit<<<(3 * 4096 + 255) / 256, 256, 0, stream>>>(
        Wrel_mid, Wroot_mid, WgH, WgL, WrH, WrL);

    // layer 0 aggregation (1-channel) + fused pre-transform -> G1,R1 (set A)
    k_agg_scalar<<<(NN + 255) / 256, 256, 0, stream>>>(offs, ends, pairs, x, agg0);
    k_l0pre<<<NN / 16, 256, 0, stream>>>(
        agg0, x, Wrel0, brel0, Wroot0,
        WgH, WgL, WrH, WrL, brel_mid, GbA, RbA);

    // mid layer 1: consume set A, produce set B (weights index 1)
    k_aggfused<false><<<NN / 16, 256, 0, stream>>>(
        offs, ends, pairs, GbA, RbA,
        WgH + 4096, WgL + 4096, WrH + 4096, WrL + 4096, brel_mid + HID,
        GbB, RbB, WrelL, WrootL, sarr, rarr);
    // mid layer 2: consume set B, produce set A (weights index 2)
    k_aggfused<false><<<NN / 16, 256, 0, stream>>>(
        offs, ends, pairs, GbB, RbB,
        WgH + 2 * 4096, WgL + 2 * 4096, WrH + 2 * 4096, WrL + 2 * 4096,
        brel_mid + 2 * HID, GbA, RbA, WrelL, WrootL, sarr, rarr);
    // mid layer 3 (LAST): consume set A, produce s/r scalars
    k_aggfused<true><<<NN / 16, 256, 0, stream>>>(
        offs, ends, pairs, GbA, RbA,
        WgH, WgL, WrH, WrL, brel_mid,
        GbB, RbB, WrelL, WrootL, sarr, rarr);

    // final edge pass on scalars
    k_last<<<(NN + 255) / 256, 256, 0, stream>>>(offs, ends, pairs, sarr, rarr, brelL, out);
}